// Round 15
// baseline (2228.285 us; speedup 1.0000x reference)
//
#include <hip/hip_runtime.h>
#include <hip/hip_bf16.h>
#include <cstdint>

#define S_LEN 1024
#define DMODEL 1352
#define TD 4056
#define DFFN 2704
#define NHEAD 8
#define HDIM 169
#define NLAYER 7
#define LDAP 1408   // 1352 -> 22*64
#define KP2 2752    // 2704 -> 43*64
#define QS 1536     // 8 heads * 192
#define HP 192      // head dim padded to 3*64

typedef __attribute__((ext_vector_type(8))) short short8;
typedef __attribute__((ext_vector_type(4))) float f32x4;
typedef __attribute__((ext_vector_type(2))) unsigned short us2;
typedef __attribute__((ext_vector_type(4))) unsigned short us4;

__device__ __forceinline__ unsigned short f2bf(float f) {
    union { float f; unsigned int u; } c; c.f = f;
    unsigned int r = (c.u + 0x7fffu + ((c.u >> 16) & 1u)) >> 16;
    return (unsigned short)r;
}

__device__ __forceinline__ void g2l16(const void* g, void* l) {
    __builtin_amdgcn_global_load_lds((__attribute__((address_space(1))) void*)g,
                                     (__attribute__((address_space(3))) void*)l,
                                     16, 0, 0);
}

// ---------------- routing ----------------
__global__ __launch_bounds__(256) void route_k(const float* __restrict__ x,
                                               int* __restrict__ perm,
                                               int* __restrict__ pcnt) {
    const int tid = threadIdx.x;
    const int lane = tid & 63;
    const int w = tid >> 6;
    for (int i = tid; i < 4096; i += 256) perm[i] = -1;
    __syncthreads();
    int base = 0;
    for (int c = 0; c < 16; ++c) {
        const int t = c * 64 + lane;
        const float* xr = x + (long long)t * DMODEL;
        float best = xr[0]; int bi = 0;
        #pragma unroll
        for (int j = 1; j < 16; ++j) { float v = xr[j]; if (v > best) { best = v; bi = j; } }
        const bool match = ((bi & 3) == w);
        unsigned long long mb = __ballot(match);
        int pos = __popcll(mb & ((1ull << lane) - 1ull));
        if (match) perm[w * 1024 + base + pos] = t;
        base += __popcll(mb);
    }
    if (lane == 0) pcnt[w] = (base + 127) & ~127;
}

// ---------------- r11 tconv tile (proven): 32x32, [32][33] LDS ----------------
__device__ __forceinline__ void tconv_tile(const float* __restrict__ src,
    unsigned short* __restrict__ dst, int K, int N, int Kp, int kt, int nt,
    float (*t)[33])
{
    const int k0 = kt * 32, n0 = nt * 32;
    const int tx = threadIdx.x & 31, ty = threadIdx.x >> 5;
    #pragma unroll
    for (int i = 0; i < 4; ++i) {
        int k = k0 + ty + i * 8, n = n0 + tx;
        t[ty + i * 8][tx] = (k < K && n < N) ? src[(long long)k * N + n] : 0.f;
    }
    __syncthreads();
    #pragma unroll
    for (int i = 0; i < 2; ++i) {
        int s = threadIdx.x + i * 256;
        int nr = s >> 4;
        int kp = (s & 15) * 2;
        int n = n0 + nr;
        if (n < N) {
            us2 w; w.x = f2bf(t[kp][nr]); w.y = f2bf(t[kp + 1][nr]);
            *(us2*)&dst[(long long)n * Kp + k0 + kp] = w;
        }
    }
}

__device__ __forceinline__ void ln_row(const float* __restrict__ h,
    const float* __restrict__ g, const float* __restrict__ b,
    unsigned short* __restrict__ out, int row, float* sA, float* sB)
{
    const float* hr = h + (long long)row * DMODEL;
    float s = 0.f, s2 = 0.f;
    for (int j = threadIdx.x; j < DMODEL; j += 256) { float v = hr[j]; s += v; s2 += v * v; }
    #pragma unroll
    for (int o = 32; o; o >>= 1) { s += __shfl_xor(s, o, 64); s2 += __shfl_xor(s2, o, 64); }
    const int lane = threadIdx.x & 63, wid = threadIdx.x >> 6;
    if (lane == 0) { sA[wid] = s; sB[wid] = s2; }
    __syncthreads();
    s = sA[0] + sA[1] + sA[2] + sA[3];
    s2 = sB[0] + sB[1] + sB[2] + sB[3];
    const float mu = s / DMODEL;
    const float rstd = rsqrtf(fmaxf(s2 / DMODEL - mu * mu, 0.f) + 1e-5f);
    unsigned short* orow = out + (long long)row * LDAP;
    for (int j = threadIdx.x; j < LDAP; j += 256) {
        float v = (j < DMODEL) ? (hr[j] - mu) * rstd * g[j] + b[j] : 0.f;
        orow[j] = f2bf(v);
    }
}

#define NB_QKV (44 * 127)
#define NB_WO  (44 * 43)
#define NB_W1  (44 * 85 * 4)
#define NB_W2  (86 * 43 * 4)

// ------- prep1: ALL weight tconv (wqkv, wo, w1, w2) || LN1 (one dispatch) -------
__global__ __launch_bounds__(256) void prep1_k(
    const float* __restrict__ wqkv_l, const float* __restrict__ wo_l,
    const float* __restrict__ w1_l, const float* __restrict__ w2_l,
    unsigned short* __restrict__ wqkvT, unsigned short* __restrict__ woT,
    unsigned short* __restrict__ w1T, unsigned short* __restrict__ w2T,
    const float* __restrict__ h, const float* __restrict__ g,
    const float* __restrict__ bb, unsigned short* __restrict__ lnA)
{
    __shared__ __align__(16) float t[32][33];
    __shared__ float sA[4], sB[4];
    int b = blockIdx.x;
    if (b < NB_QKV) {
        tconv_tile(wqkv_l, wqkvT, DMODEL, TD, LDAP, b % 44, b / 44, t);
        return;
    }
    b -= NB_QKV;
    if (b < NB_WO) {
        tconv_tile(wo_l, woT, DMODEL, DMODEL, LDAP, b % 44, b / 44, t);
        return;
    }
    b -= NB_WO;
    if (b < NB_W1) {
        const int kt = b % 44, rem = b / 44;
        const int nt = rem % 85, z = rem / 85;
        tconv_tile(w1_l + (long long)z * DMODEL * DFFN,
                   w1T + (long long)z * 2816 * LDAP,
                   DMODEL, DFFN, LDAP, kt, nt, t);
        return;
    }
    b -= NB_W1;
    if (b < NB_W2) {
        const int kt = b % 86, rem = b / 86;
        const int nt = rem % 43, z = rem / 43;
        tconv_tile(w2_l + (long long)z * DFFN * DMODEL,
                   w2T + (long long)z * 1408 * KP2,
                   DFFN, DMODEL, KP2, kt, nt, t);
        return;
    }
    b -= NB_W2;
    ln_row(h, g, bb, lnA, b, sA, sB);
}

// ---------------- ln2: tiny LN-only dispatch ----------------
__global__ __launch_bounds__(256) void ln2_k(
    const float* __restrict__ h, const float* __restrict__ g,
    const float* __restrict__ bb, unsigned short* __restrict__ lnA)
{
    __shared__ float sA[4], sB[4];
    ln_row(h, g, bb, lnA, blockIdx.x, sA, sB);
}

// ---------------- causal row softmax (scores f32 -> P bf16) ----------------
__global__ __launch_bounds__(256) void softmax_k(const float* __restrict__ scores,
                                                 unsigned short* __restrict__ P,
                                                 float scale) {
    const int i = blockIdx.x;
    const long long rb = ((long long)blockIdx.y * 1024 + i) * 1024;
    const float* srow = scores + rb;
    unsigned short* prow = P + rb;
    const int n = i + 1;
    float mx = -3.4e38f;
    for (int j = threadIdx.x; j < n; j += 256) mx = fmaxf(mx, srow[j]);
    __shared__ float sA[4], sB[4];
    #pragma unroll
    for (int o = 32; o; o >>= 1) mx = fmaxf(mx, __shfl_xor(mx, o, 64));
    const int lane = threadIdx.x & 63, wid = threadIdx.x >> 6;
    if (lane == 0) sA[wid] = mx;
    __syncthreads();
    mx = fmaxf(fmaxf(sA[0], sA[1]), fmaxf(sA[2], sA[3])) * scale;
    float sum = 0.f;
    for (int j = threadIdx.x; j < n; j += 256) sum += __expf(srow[j] * scale - mx);
    #pragma unroll
    for (int o = 32; o; o >>= 1) sum += __shfl_xor(sum, o, 64);
    if (lane == 0) sB[wid] = sum;
    __syncthreads();
    const float inv = 1.f / (sB[0] + sB[1] + sB[2] + sB[3]);
    const int nz = ((i >> 7) + 1) << 7;
    for (int j = threadIdx.x; j < nz; j += 256) {
        float p = (j < n) ? __expf(srow[j] * scale - mx) * inv : 0.f;
        prow[j] = f2bf(p);
    }
}

// ---------------- pipelined bf16 MFMA GEMM, 128x128x64, 8 waves ----------------
// 5 LDS buffers (160 KB = full CU LDS), 4-deep prefetch, vmcnt(12): 3 tiles
// stay in flight across the wait -> ~750+ cy latency cover. Bank-conflict fix
// as r14 (both-sides XOR involution, 16B slot s of row r at s^(r&7)).
// Race audit: buffer (t+4)%5 written at iter t was last READ at iter t-1;
// the write is issued after barrier(t), by which all waves' t-1 ds_reads
// completed (lgkmcnt before their MFMAs). End drain per round-3 rule.
template<int EPI, bool GATHER, int CAUSAL>
__global__ __launch_bounds__(512) void gemm2_k(
    const unsigned short* __restrict__ A_, int lda, long long zsA,
    const unsigned short* __restrict__ B_, int ldb, long long zsB,
    void* __restrict__ C_, int ldc, long long zsC,
    const float* __restrict__ bias_, long long zsBias,
    const int* __restrict__ perm_, const int* __restrict__ pcnt,
    int N, int Kp,
    unsigned short* __restrict__ q_, unsigned short* __restrict__ k_,
    unsigned short* __restrict__ vt_) {
    const int z = blockIdx.z;
    const int gm0 = blockIdx.y * 128;
    const int n0 = blockIdx.x * 128;
    if (pcnt && gm0 >= pcnt[z]) return;
    if (CAUSAL == 1 && n0 >= gm0 + 128) return;

    const unsigned short* A = A_ + (long long)z * zsA;
    const unsigned short* B = B_ + (long long)z * zsB;
    const float* bias = bias_ ? bias_ + (long long)z * zsBias : nullptr;
    const int* perm = perm_ ? perm_ + (long long)z * 1024 : nullptr;

    __shared__ unsigned short Al[5][128 * 64];   // 80 KB
    __shared__ unsigned short Bl[5][128 * 64];   // 80 KB

    const int tid = threadIdx.x, lane = tid & 63, wid = tid >> 6;   // wid 0..7
    const int wr = wid >> 2, wc = wid & 3;                          // 2M x 4N waves
    const int l15 = lane & 15, lg = lane >> 4;

    const int sr = lane >> 3;             // 0..7
    const int scs = (lane & 7) ^ sr;      // pre-swizzled global 16B-slot

    const unsigned short* gA[2];
    const unsigned short* gB[2];
    #pragma unroll
    for (int j = 0; j < 2; ++j) {
        const int row = wid * 16 + j * 8 + sr;
        int ar = gm0 + row;
        if (GATHER) { const int p = perm[ar]; ar = (p < 0) ? 0 : p; }
        gA[j] = A + (long long)ar * lda + scs * 8;
        gB[j] = B + (long long)(n0 + row) * ldb + scs * 8;
    }
    const int ldsW = wid * 1024;

    int nt = Kp >> 6;
    if (CAUSAL == 2) { int ke = gm0 + 128; if (ke > Kp) ke = Kp; nt = ke >> 6; }

    f32x4 acc[4][2] = {};

    // prologue: issue tiles 0..3 (4 vmem ops per wave per tile; clamped)
    #pragma unroll
    for (int tt = 0; tt < 4; ++tt) {
        const int ts = (tt < nt) ? tt : nt - 1;
        const int ko = ts * 64;
        #pragma unroll
        for (int j = 0; j < 2; ++j) {
            g2l16(gA[j] + ko, &Al[tt][ldsW + j * 512]);
            g2l16(gB[j] + ko, &Bl[tt][ldsW + j * 512]);
        }
    }

    for (int t = 0; t < nt; ++t) {
        // 12 newest loads = tiles t+1..t+3 -> tile t resident after this wait
        asm volatile("s_waitcnt vmcnt(12)" ::: "memory");
        __builtin_amdgcn_s_barrier();
        __builtin_amdgcn_sched_barrier(0);
        // issue tile t+4 into buffer (t+4)%5 (clamped dummy keeps vmcnt uniform)
        {
            const int ts = (t + 4 < nt) ? t + 4 : nt - 1;
            const int ko = ts * 64;
            const int bi = (t + 4) % 5;
            #pragma unroll
            for (int j = 0; j < 2; ++j) {
                g2l16(gA[j] + ko, &Al[bi][ldsW + j * 512]);
                g2l16(gB[j] + ko, &Bl[bi][ldsW + j * 512]);
            }
        }
        const int cur = t % 5;
        short8 af[4][2], bfv[2][2];
        #pragma unroll
        for (int m = 0; m < 4; ++m)
            #pragma unroll
            for (int s = 0; s < 2; ++s)
                af[m][s] = *(const short8*)&Al[cur][(wr * 64 + m * 16 + l15) * 64 +
                                                    (((s * 4 + lg) ^ (l15 & 7)) * 8)];
        #pragma unroll
        for (int n = 0; n < 2; ++n)
            #pragma unroll
            for (int s = 0; s < 2; ++s)
                bfv[n][s] = *(const short8*)&Bl[cur][(wc * 32 + n * 16 + l15) * 64 +
                                                     (((s * 4 + lg) ^ (l15 & 7)) * 8)];
        #pragma unroll
        for (int s = 0; s < 2; ++s)
            #pragma unroll
            for (int m = 0; m < 4; ++m)
                #pragma unroll
                for (int n = 0; n < 2; ++n)
                    acc[m][n] = __builtin_amdgcn_mfma_f32_16x16x32_bf16(af[m][s], bfv[n][s], acc[m][n], 0, 0, 0);
    }

    // DRAIN: no LDS-DMA may be in flight at s_endpgm (round-3 race)
    asm volatile("s_waitcnt vmcnt(0) lgkmcnt(0)" ::: "memory");

    const int lq = lg * 4;
    #pragma unroll
    for (int m = 0; m < 4; ++m) {
        const int trow = wr * 64 + m * 16 + lq;
        #pragma unroll
        for (int n = 0; n < 2; ++n) {
            const int col = n0 + wc * 32 + n * 16 + l15;
            if (col >= N) continue;
            const float bv = bias ? bias[col] : 0.f;
            if (EPI == 5) {
                const int role = col / 1352;
                const int within = col - role * 1352;
                const int hh = within / 169;
                const int dd = within - hh * 169;
                if (role == 2) {
                    us4 pk;
                    #pragma unroll
                    for (int r = 0; r < 4; ++r) pk[r] = f2bf(acc[m][n][r] + bv);
                    *(us4*)&vt_[(long long)(hh * 256 + dd) * 1024 + gm0 + trow] = pk;
                } else {
                    unsigned short* dstb = role ? k_ : q_;
                    #pragma unroll
                    for (int r = 0; r < 4; ++r)
                        dstb[(long long)(gm0 + trow + r) * QS + hh * HP + dd] =
                            f2bf(acc[m][n][r] + bv);
                }
            } else {
                #pragma unroll
                for (int r = 0; r < 4; ++r) {
                    const int grow = gm0 + trow + r;
                    const float v = acc[m][n][r] + bv;
                    if (EPI == 0) {
                        ((float*)C_)[(long long)z * zsC + (long long)grow * ldc + col] = v;
                    } else if (EPI == 1) {
                        const int tok = perm[grow];
                        ((unsigned short*)C_)[(long long)z * zsC + (long long)grow * ldc + col] =
                            (tok >= 0) ? f2bf(fmaxf(v, 0.f)) : (unsigned short)0;
                    } else if (EPI == 2) {
                        ((float*)C_)[(long long)grow * ldc + col] += v;
                    } else if (EPI == 3) {
                        const int tok = perm[grow];
                        if (tok >= 0) ((float*)C_)[(long long)tok * ldc + col] += v;
                    } else if (EPI == 6) {
                        ((unsigned short*)C_)[(long long)grow * ldc + z * 169 + col] = f2bf(v);
                    }
                }
            }
        }
    }
}

extern "C" void kernel_launch(void* const* d_in, const int* in_sizes, int n_in,
                              void* d_out, int out_size, void* d_ws, size_t ws_size,
                              hipStream_t stream) {
    const float* x     = (const float*)d_in[0];
    const float* ln1_g = (const float*)d_in[1];
    const float* ln1_b = (const float*)d_in[2];
    const float* wqkv  = (const float*)d_in[3];
    const float* bqkv  = (const float*)d_in[4];
    const float* wo    = (const float*)d_in[5];
    const float* bo    = (const float*)d_in[6];
    const float* ln2_g = (const float*)d_in[7];
    const float* ln2_b = (const float*)d_in[8];
    const float* w1    = (const float*)d_in[9];
    const float* b1    = (const float*)d_in[10];
    const float* w2    = (const float*)d_in[11];
    const float* b2    = (const float*)d_in[12];

    float* h = (float*)d_out;

    char* w = (char*)d_ws;
    auto alloc = [&](size_t bytes) { void* p = w; w += (bytes + 255) & ~255ull; return p; };
    unsigned short* lnA   = (unsigned short*)alloc((size_t)S_LEN * LDAP * 2);
    unsigned short* qb    = (unsigned short*)alloc((size_t)S_LEN * QS * 2);
    unsigned short* kb    = (unsigned short*)alloc((size_t)S_LEN * QS * 2);
    unsigned short* VT    = (unsigned short*)alloc((size_t)NHEAD * 256 * 1024 * 2);
    unsigned short* obufb = (unsigned short*)alloc((size_t)S_LEN * LDAP * 2);
    unsigned short* hid   = (unsigned short*)alloc((size_t)4096 * KP2 * 2);
    unsigned short* wqkvT = (unsigned short*)alloc((size_t)4096 * LDAP * 2);
    unsigned short* woT   = (unsigned short*)alloc((size_t)1408 * LDAP * 2);
    unsigned short* w1T   = (unsigned short*)alloc((size_t)4 * 2816 * LDAP * 2);  // 31.7 MB
    unsigned short* w2T   = (unsigned short*)alloc((size_t)4 * 1408 * KP2 * 2);   // 31.0 MB
    float*          scores= (float*)alloc((size_t)NHEAD * 1024 * 1024 * 4);       // 33.6 MB
    unsigned short* Pbuf  = (unsigned short*)alloc((size_t)NHEAD * 1024 * 1024 * 2); // 16.8 MB
    int* perm = (int*)alloc(4096 * 4);
    int* pcnt = (int*)alloc(64);

    hipMemcpyAsync(h, x, (size_t)S_LEN * DMODEL * 4, hipMemcpyDeviceToDevice, stream);
    // q/k head-pad slots enter the scores MFMA -> must be zero
    hipMemsetAsync(qb, 0, (size_t)S_LEN * QS * 2, stream);
    hipMemsetAsync(kb, 0, (size_t)S_LEN * QS * 2, stream);
    route_k<<<1, 256, 0, stream>>>(x, perm, pcnt);

    const float scale = 1.0f / 13.0f;

    for (int l = 0; l < NLAYER; ++l) {
        const float* wqkv_l = wqkv + (long long)l * DMODEL * TD;
        const float* wo_l   = wo   + (long long)l * DMODEL * DMODEL;
        const float* w1_l   = w1   + (long long)l * 4 * DMODEL * DFFN;
        const float* w2_l   = w2   + (long long)l * 4 * DFFN * DMODEL;

        // fused: ALL weight tconv || LN1 (one big dispatch)
        prep1_k<<<NB_QKV + NB_WO + NB_W1 + NB_W2 + 1024, 256, 0, stream>>>(
            wqkv_l, wo_l, w1_l, w2_l, wqkvT, woT, w1T, w2T,
            h, ln1_g + l * DMODEL, ln1_b + l * DMODEL, lnA);
        // QKV -> split bf16 q/k (head-padded) + V transposed
        gemm2_k<5, false, 0><<<dim3(32, 8, 1), 512, 0, stream>>>(
            lnA, LDAP, 0, wqkvT, LDAP, 0, nullptr, 0, 0,
            bqkv + l * TD, 0, nullptr, nullptr, TD, LDAP, qb, kb, VT);
        // scores = q @ k^T per head (causal tiles only)
        gemm2_k<0, false, 1><<<dim3(8, 8, 8), 512, 0, stream>>>(
            qb, QS, HP, kb, QS, HP, scores, 1024, 1024 * 1024,
            nullptr, 0, nullptr, nullptr, 1024, HP, nullptr, nullptr, nullptr);
        softmax_k<<<dim3(1024, NHEAD), 256, 0, stream>>>(scores, Pbuf, scale);
        // o = P @ v per head -> compact bf16 [1024][1408]
        gemm2_k<6, false, 2><<<dim3(2, 8, 8), 512, 0, stream>>>(
            Pbuf, 1024, 1024 * 1024, VT, 1024, 256 * 1024, obufb, LDAP, 0,
            nullptr, 0, nullptr, nullptr, HDIM, 1024, nullptr, nullptr, nullptr);
        // h += o @ wo + bo
        gemm2_k<2, false, 0><<<dim3(11, 8, 1), 512, 0, stream>>>(
            obufb, LDAP, 0, woT, LDAP, 0, h, DMODEL, 0,
            bo + l * DMODEL, 0, nullptr, nullptr, DMODEL, LDAP, nullptr, nullptr, nullptr);

        // LN2 (tiny)
        ln2_k<<<1024, 256, 0, stream>>>(h, ln2_g + l * DMODEL, ln2_b + l * DMODEL, lnA);
        // hid = relu(gather(lnA) @ w1[e] + b1[e]) -> bf16
        gemm2_k<1, true, 0><<<dim3(22, 8, 4), 512, 0, stream>>>(
            lnA, LDAP, 0, w1T, LDAP, (long long)2816 * LDAP,
            hid, KP2, (long long)1024 * KP2,
            b1 + (long long)l * 4 * DFFN, DFFN, perm, pcnt, DFFN, LDAP,
            nullptr, nullptr, nullptr);
        // h[tok] += hid @ w2[e] + b2[e]
        gemm2_k<3, false, 0><<<dim3(11, 8, 4), 512, 0, stream>>>(
            hid, KP2, (long long)1024 * KP2, w2T, KP2, (long long)1408 * KP2,
            h, DMODEL, 0,
            b2 + (long long)l * 4 * DMODEL, DMODEL, perm, pcnt, DMODEL, KP2,
            nullptr, nullptr, nullptr);
    }
}

// Round 16
// 1819.850 us; speedup vs baseline: 1.2244x; 1.2244x over previous
//
#include <hip/hip_runtime.h>
#include <hip/hip_bf16.h>
#include <cstdint>

#define S_LEN 1024
#define DMODEL 1352
#define TD 4056
#define DFFN 2704
#define NHEAD 8
#define HDIM 169
#define NLAYER 7
#define LDAP 1408   // 1352 -> 22*64
#define KP2 2752    // 2704 -> 43*64
#define QS 1536     // 8 heads * 192
#define HP 192      // head dim padded to 3*64

typedef __attribute__((ext_vector_type(8))) short short8;
typedef __attribute__((ext_vector_type(4))) float f32x4;
typedef __attribute__((ext_vector_type(2))) unsigned short us2;
typedef __attribute__((ext_vector_type(4))) unsigned short us4;

__device__ __forceinline__ unsigned short f2bf(float f) {
    union { float f; unsigned int u; } c; c.f = f;
    unsigned int r = (c.u + 0x7fffu + ((c.u >> 16) & 1u)) >> 16;
    return (unsigned short)r;
}

__device__ __forceinline__ void g2l16(const void* g, void* l) {
    __builtin_amdgcn_global_load_lds((__attribute__((address_space(1))) void*)g,
                                     (__attribute__((address_space(3))) void*)l,
                                     16, 0, 0);
}

// ---------------- routing ----------------
__global__ __launch_bounds__(256) void route_k(const float* __restrict__ x,
                                               int* __restrict__ perm,
                                               int* __restrict__ pcnt) {
    const int tid = threadIdx.x;
    const int lane = tid & 63;
    const int w = tid >> 6;
    for (int i = tid; i < 4096; i += 256) perm[i] = -1;
    __syncthreads();
    int base = 0;
    for (int c = 0; c < 16; ++c) {
        const int t = c * 64 + lane;
        const float* xr = x + (long long)t * DMODEL;
        float best = xr[0]; int bi = 0;
        #pragma unroll
        for (int j = 1; j < 16; ++j) { float v = xr[j]; if (v > best) { best = v; bi = j; } }
        const bool match = ((bi & 3) == w);
        unsigned long long mb = __ballot(match);
        int pos = __popcll(mb & ((1ull << lane) - 1ull));
        if (match) perm[w * 1024 + base + pos] = t;
        base += __popcll(mb);
    }
    if (lane == 0) pcnt[w] = (base + 127) & ~127;
}

// ---------------- r11 tconv tile (proven): 32x32, [32][33] LDS ----------------
__device__ __forceinline__ void tconv_tile(const float* __restrict__ src,
    unsigned short* __restrict__ dst, int K, int N, int Kp, int kt, int nt,
    float (*t)[33])
{
    const int k0 = kt * 32, n0 = nt * 32;
    const int tx = threadIdx.x & 31, ty = threadIdx.x >> 5;
    #pragma unroll
    for (int i = 0; i < 4; ++i) {
        int k = k0 + ty + i * 8, n = n0 + tx;
        t[ty + i * 8][tx] = (k < K && n < N) ? src[(long long)k * N + n] : 0.f;
    }
    __syncthreads();
    #pragma unroll
    for (int i = 0; i < 2; ++i) {
        int s = threadIdx.x + i * 256;
        int nr = s >> 4;
        int kp = (s & 15) * 2;
        int n = n0 + nr;
        if (n < N) {
            us2 w; w.x = f2bf(t[kp][nr]); w.y = f2bf(t[kp + 1][nr]);
            *(us2*)&dst[(long long)n * Kp + k0 + kp] = w;
        }
    }
}

__device__ __forceinline__ void ln_row(const float* __restrict__ h,
    const float* __restrict__ g, const float* __restrict__ b,
    unsigned short* __restrict__ out, int row, float* sA, float* sB)
{
    const float* hr = h + (long long)row * DMODEL;
    float s = 0.f, s2 = 0.f;
    for (int j = threadIdx.x; j < DMODEL; j += 256) { float v = hr[j]; s += v; s2 += v * v; }
    #pragma unroll
    for (int o = 32; o; o >>= 1) { s += __shfl_xor(s, o, 64); s2 += __shfl_xor(s2, o, 64); }
    const int lane = threadIdx.x & 63, wid = threadIdx.x >> 6;
    if (lane == 0) { sA[wid] = s; sB[wid] = s2; }
    __syncthreads();
    s = sA[0] + sA[1] + sA[2] + sA[3];
    s2 = sB[0] + sB[1] + sB[2] + sB[3];
    const float mu = s / DMODEL;
    const float rstd = rsqrtf(fmaxf(s2 / DMODEL - mu * mu, 0.f) + 1e-5f);
    unsigned short* orow = out + (long long)row * LDAP;
    for (int j = threadIdx.x; j < LDAP; j += 256) {
        float v = (j < DMODEL) ? (hr[j] - mu) * rstd * g[j] + b[j] : 0.f;
        orow[j] = f2bf(v);
    }
}

// ---------------- prep1: tconv(wqkv) || tconv(wo) || LN1 (r14) ----------------
__global__ __launch_bounds__(256) void prep1_k(
    const float* __restrict__ wqkv_l, const float* __restrict__ wo_l,
    unsigned short* __restrict__ wqkvT, unsigned short* __restrict__ woT,
    const float* __restrict__ h, const float* __restrict__ g,
    const float* __restrict__ bb, unsigned short* __restrict__ lnA)
{
    __shared__ __align__(16) float t[32][33];
    __shared__ float sA[4], sB[4];
    const int b = blockIdx.x;
    if (b < 44 * 127) {
        tconv_tile(wqkv_l, wqkvT, DMODEL, TD, LDAP, b % 44, b / 44, t);
    } else if (b < 44 * 127 + 44 * 43) {
        const int c = b - 44 * 127;
        tconv_tile(wo_l, woT, DMODEL, DMODEL, LDAP, c % 44, c / 44, t);
    } else {
        ln_row(h, g, bb, lnA, b - (44 * 127 + 44 * 43), sA, sB);
    }
}

// ---------------- prep2: tconv(w1) || tconv(w2) || LN2 (r14) ------------------
__global__ __launch_bounds__(256) void prep2_k(
    const float* __restrict__ w1_l, const float* __restrict__ w2_l,
    unsigned short* __restrict__ w1T, unsigned short* __restrict__ w2T,
    const float* __restrict__ h, const float* __restrict__ g,
    const float* __restrict__ bb, unsigned short* __restrict__ lnA)
{
    __shared__ __align__(16) float t[32][33];
    __shared__ float sA[4], sB[4];
    const int b = blockIdx.x;
    if (b < 44 * 85 * 4) {
        const int kt = b % 44, rem = b / 44;
        const int nt = rem % 85, z = rem / 85;
        tconv_tile(w1_l + (long long)z * DMODEL * DFFN,
                   w1T + (long long)z * 2816 * LDAP,
                   DMODEL, DFFN, LDAP, kt, nt, t);
    } else if (b < 44 * 85 * 4 + 86 * 43 * 4) {
        const int c = b - 44 * 85 * 4;
        const int kt = c % 86, rem = c / 86;
        const int nt = rem % 43, z = rem / 43;
        tconv_tile(w2_l + (long long)z * DFFN * DMODEL,
                   w2T + (long long)z * 1408 * KP2,
                   DFFN, DMODEL, KP2, kt, nt, t);
    } else {
        ln_row(h, g, bb, lnA, b - (44 * 85 * 4 + 86 * 43 * 4), sA, sB);
    }
}

// ---------------- causal row softmax (scores f32 -> P bf16) ----------------
__global__ __launch_bounds__(256) void softmax_k(const float* __restrict__ scores,
                                                 unsigned short* __restrict__ P,
                                                 float scale) {
    const int i = blockIdx.x;
    const long long rb = ((long long)blockIdx.y * 1024 + i) * 1024;
    const float* srow = scores + rb;
    unsigned short* prow = P + rb;
    const int n = i + 1;
    float mx = -3.4e38f;
    for (int j = threadIdx.x; j < n; j += 256) mx = fmaxf(mx, srow[j]);
    __shared__ float sA[4], sB[4];
    #pragma unroll
    for (int o = 32; o; o >>= 1) mx = fmaxf(mx, __shfl_xor(mx, o, 64));
    const int lane = threadIdx.x & 63, wid = threadIdx.x >> 6;
    if (lane == 0) sA[wid] = mx;
    __syncthreads();
    mx = fmaxf(fmaxf(sA[0], sA[1]), fmaxf(sA[2], sA[3])) * scale;
    float sum = 0.f;
    for (int j = threadIdx.x; j < n; j += 256) sum += __expf(srow[j] * scale - mx);
    #pragma unroll
    for (int o = 32; o; o >>= 1) sum += __shfl_xor(sum, o, 64);
    if (lane == 0) sB[wid] = sum;
    __syncthreads();
    const float inv = 1.f / (sB[0] + sB[1] + sB[2] + sB[3]);
    const int nz = ((i >> 7) + 1) << 7;
    for (int j = threadIdx.x; j < nz; j += 256) {
        float p = (j < n) ? __expf(srow[j] * scale - mx) * inv : 0.f;
        prow[j] = f2bf(p);
    }
}

// ---------------- pipelined bf16 MFMA GEMM, 64x128x64, 8 waves ----------------
// OCCUPANCY CHANGE vs r14: 64-row M-tile, 3 LDS buffers (72 KB) -> 2 blocks/CU,
// 4 waves/SIMD; cross-block overlap (one block's MFMA hides the other's staging,
// no shared barrier). Per wave: 3 g2l16/tile (A:1, B:2), vmcnt(6) = 2 tiles in
// flight, 8 MFMA/step, acc[2][2]. Swizzle as r14: slot s of row r at s^(r&7).
template<int EPI, bool GATHER, int CAUSAL>
__global__ __launch_bounds__(512) void gemm2_k(
    const unsigned short* __restrict__ A_, int lda, long long zsA,
    const unsigned short* __restrict__ B_, int ldb, long long zsB,
    void* __restrict__ C_, int ldc, long long zsC,
    const float* __restrict__ bias_, long long zsBias,
    const int* __restrict__ perm_, const int* __restrict__ pcnt,
    int N, int Kp,
    unsigned short* __restrict__ q_, unsigned short* __restrict__ k_,
    unsigned short* __restrict__ vt_) {
    const int z = blockIdx.z;
    const int gm0 = blockIdx.y * 64;
    const int n0 = blockIdx.x * 128;
    if (pcnt && gm0 >= pcnt[z]) return;
    if (CAUSAL == 1 && n0 >= gm0 + 64) return;

    const unsigned short* A = A_ + (long long)z * zsA;
    const unsigned short* B = B_ + (long long)z * zsB;
    const float* bias = bias_ ? bias_ + (long long)z * zsBias : nullptr;
    const int* perm = perm_ ? perm_ + (long long)z * 1024 : nullptr;

    __shared__ unsigned short Al[3][64 * 64];    // 24 KB
    __shared__ unsigned short Bl[3][128 * 64];   // 48 KB

    const int tid = threadIdx.x, lane = tid & 63, wid = tid >> 6;   // wid 0..7
    const int wr = wid >> 2, wc = wid & 3;                          // 2M x 4N waves
    const int l15 = lane & 15, lg = lane >> 4;

    const int sr = lane >> 3;             // 0..7
    const int scs = (lane & 7) ^ sr;      // pre-swizzled global 16B-slot

    // A staging: wave wid stages rows wid*8..+7 (1 load)
    const unsigned short* gA;
    {
        const int row = wid * 8 + sr;
        int ar = gm0 + row;
        if (GATHER) { const int p = perm[ar]; ar = (p < 0) ? 0 : p; }
        gA = A + (long long)ar * lda + scs * 8;
    }
    // B staging: wave wid stages rows wid*16+j*8..+7 (2 loads)
    const unsigned short* gB[2];
    #pragma unroll
    for (int j = 0; j < 2; ++j)
        gB[j] = B + (long long)(n0 + wid * 16 + j * 8 + sr) * ldb + scs * 8;

    const int ldsA = wid * 512;           // elements
    const int ldsB = wid * 1024;

    int nt = Kp >> 6;
    if (CAUSAL == 2) { int ke = gm0 + 64; if (ke > Kp) ke = Kp; nt = ke >> 6; }

    f32x4 acc[2][2] = {};

    // prologue: issue tiles 0,1 (3 vmem ops per wave per tile; clamped)
    #pragma unroll
    for (int tt = 0; tt < 2; ++tt) {
        const int ts = (tt < nt) ? tt : nt - 1;
        const int ko = ts * 64;
        g2l16(gA + ko, &Al[tt][ldsA]);
        g2l16(gB[0] + ko, &Bl[tt][ldsB]);
        g2l16(gB[1] + ko, &Bl[tt][ldsB + 512]);
    }

    for (int t = 0; t < nt; ++t) {
        // 6 newest loads = tiles t+1,t+2 -> tile t resident after this wait
        asm volatile("s_waitcnt vmcnt(6)" ::: "memory");
        __builtin_amdgcn_s_barrier();
        __builtin_amdgcn_sched_barrier(0);
        // issue tile t+2 into buffer (t+2)%3 (clamped dummy keeps vmcnt uniform)
        {
            const int ts = (t + 2 < nt) ? t + 2 : nt - 1;
            const int ko = ts * 64;
            const int bi = (t + 2) % 3;
            g2l16(gA + ko, &Al[bi][ldsA]);
            g2l16(gB[0] + ko, &Bl[bi][ldsB]);
            g2l16(gB[1] + ko, &Bl[bi][ldsB + 512]);
        }
        const int cur = t % 3;
        short8 af[2][2], bfv[2][2];
        #pragma unroll
        for (int m = 0; m < 2; ++m)
            #pragma unroll
            for (int s = 0; s < 2; ++s)
                af[m][s] = *(const short8*)&Al[cur][(wr * 32 + m * 16 + l15) * 64 +
                                                    (((s * 4 + lg) ^ (l15 & 7)) * 8)];
        #pragma unroll
        for (int n = 0; n < 2; ++n)
            #pragma unroll
            for (int s = 0; s < 2; ++s)
                bfv[n][s] = *(const short8*)&Bl[cur][(wc * 32 + n * 16 + l15) * 64 +
                                                     (((s * 4 + lg) ^ (l15 & 7)) * 8)];
        #pragma unroll
        for (int s = 0; s < 2; ++s)
            #pragma unroll
            for (int m = 0; m < 2; ++m)
                #pragma unroll
                for (int n = 0; n < 2; ++n)
                    acc[m][n] = __builtin_amdgcn_mfma_f32_16x16x32_bf16(af[m][s], bfv[n][s], acc[m][n], 0, 0, 0);
    }

    // DRAIN: no LDS-DMA may be in flight at s_endpgm (round-3 race)
    asm volatile("s_waitcnt vmcnt(0) lgkmcnt(0)" ::: "memory");

    const int lq = lg * 4;
    #pragma unroll
    for (int m = 0; m < 2; ++m) {
        const int trow = wr * 32 + m * 16 + lq;
        #pragma unroll
        for (int n = 0; n < 2; ++n) {
            const int col = n0 + wc * 32 + n * 16 + l15;
            if (col >= N) continue;
            const float bv = bias ? bias[col] : 0.f;
            if (EPI == 5) {
                const int role = col / 1352;
                const int within = col - role * 1352;
                const int hh = within / 169;
                const int dd = within - hh * 169;
                if (role == 2) {
                    us4 pk;
                    #pragma unroll
                    for (int r = 0; r < 4; ++r) pk[r] = f2bf(acc[m][n][r] + bv);
                    *(us4*)&vt_[(long long)(hh * 256 + dd) * 1024 + gm0 + trow] = pk;
                } else {
                    unsigned short* dstb = role ? k_ : q_;
                    #pragma unroll
                    for (int r = 0; r < 4; ++r)
                        dstb[(long long)(gm0 + trow + r) * QS + hh * HP + dd] =
                            f2bf(acc[m][n][r] + bv);
                }
            } else {
                #pragma unroll
                for (int r = 0; r < 4; ++r) {
                    const int grow = gm0 + trow + r;
                    const float v = acc[m][n][r] + bv;
                    if (EPI == 0) {
                        ((float*)C_)[(long long)z * zsC + (long long)grow * ldc + col] = v;
                    } else if (EPI == 1) {
                        const int tok = perm[grow];
                        ((unsigned short*)C_)[(long long)z * zsC + (long long)grow * ldc + col] =
                            (tok >= 0) ? f2bf(fmaxf(v, 0.f)) : (unsigned short)0;
                    } else if (EPI == 2) {
                        ((float*)C_)[(long long)grow * ldc + col] += v;
                    } else if (EPI == 3) {
                        const int tok = perm[grow];
                        if (tok >= 0) ((float*)C_)[(long long)tok * ldc + col] += v;
                    } else if (EPI == 6) {
                        ((unsigned short*)C_)[(long long)grow * ldc + z * 169 + col] = f2bf(v);
                    }
                }
            }
        }
    }
}

extern "C" void kernel_launch(void* const* d_in, const int* in_sizes, int n_in,
                              void* d_out, int out_size, void* d_ws, size_t ws_size,
                              hipStream_t stream) {
    const float* x     = (const float*)d_in[0];
    const float* ln1_g = (const float*)d_in[1];
    const float* ln1_b = (const float*)d_in[2];
    const float* wqkv  = (const float*)d_in[3];
    const float* bqkv  = (const float*)d_in[4];
    const float* wo    = (const float*)d_in[5];
    const float* bo    = (const float*)d_in[6];
    const float* ln2_g = (const float*)d_in[7];
    const float* ln2_b = (const float*)d_in[8];
    const float* w1    = (const float*)d_in[9];
    const float* b1    = (const float*)d_in[10];
    const float* w2    = (const float*)d_in[11];
    const float* b2    = (const float*)d_in[12];

    float* h = (float*)d_out;

    char* w = (char*)d_ws;
    auto alloc = [&](size_t bytes) { void* p = w; w += (bytes + 255) & ~255ull; return p; };
    unsigned short* lnA   = (unsigned short*)alloc((size_t)S_LEN * LDAP * 2);
    unsigned short* qb    = (unsigned short*)alloc((size_t)S_LEN * QS * 2);
    unsigned short* kb    = (unsigned short*)alloc((size_t)S_LEN * QS * 2);
    unsigned short* VT    = (unsigned short*)alloc((size_t)NHEAD * 256 * 1024 * 2);
    unsigned short* obufb = (unsigned short*)alloc((size_t)S_LEN * LDAP * 2);
    unsigned short* hid   = (unsigned short*)alloc((size_t)4096 * KP2 * 2);
    unsigned short* wqkvT = (unsigned short*)alloc((size_t)4096 * LDAP * 2);
    unsigned short* woT   = (unsigned short*)alloc((size_t)1408 * LDAP * 2);
    char*           U     = (char*)alloc((size_t)64000000);   // union (time-aliased, L3-hot)
    int* perm = (int*)alloc(4096 * 4);
    int* pcnt = (int*)alloc(64);

    float*          scores = (float*)U;
    unsigned short* Pbuf   = (unsigned short*)(U + (size_t)NHEAD * 1024 * 1024 * 4);
    unsigned short* w1T    = (unsigned short*)U;
    unsigned short* w2T    = (unsigned short*)(U + (size_t)4 * 2816 * LDAP * 2);

    hipMemcpyAsync(h, x, (size_t)S_LEN * DMODEL * 4, hipMemcpyDeviceToDevice, stream);
    // q/k head-pad slots enter the scores MFMA -> must be zero
    hipMemsetAsync(qb, 0, (size_t)S_LEN * QS * 2, stream);
    hipMemsetAsync(kb, 0, (size_t)S_LEN * QS * 2, stream);
    route_k<<<1, 256, 0, stream>>>(x, perm, pcnt);

    const float scale = 1.0f / 13.0f;

    for (int l = 0; l < NLAYER; ++l) {
        const float* wqkv_l = wqkv + (long long)l * DMODEL * TD;
        const float* wo_l   = wo   + (long long)l * DMODEL * DMODEL;
        const float* w1_l   = w1   + (long long)l * 4 * DMODEL * DFFN;
        const float* w2_l   = w2   + (long long)l * 4 * DFFN * DMODEL;

        // fused: tconv(wqkv) || tconv(wo) || LN1
        prep1_k<<<44 * 127 + 44 * 43 + 1024, 256, 0, stream>>>(
            wqkv_l, wo_l, wqkvT, woT, h, ln1_g + l * DMODEL, ln1_b + l * DMODEL, lnA);
        // QKV -> split bf16 q/k (head-padded) + V transposed
        gemm2_k<5, false, 0><<<dim3(32, 16, 1), 512, 0, stream>>>(
            lnA, LDAP, 0, wqkvT, LDAP, 0, nullptr, 0, 0,
            bqkv + l * TD, 0, nullptr, nullptr, TD, LDAP, qb, kb, VT);
        // scores = q @ k^T per head (causal tiles only)
        gemm2_k<0, false, 1><<<dim3(8, 16, 8), 512, 0, stream>>>(
            qb, QS, HP, kb, QS, HP, scores, 1024, 1024 * 1024,
            nullptr, 0, nullptr, nullptr, 1024, HP, nullptr, nullptr, nullptr);
        softmax_k<<<dim3(1024, NHEAD), 256, 0, stream>>>(scores, Pbuf, scale);
        // o = P @ v per head -> compact bf16 [1024][1408]
        gemm2_k<6, false, 2><<<dim3(2, 16, 8), 512, 0, stream>>>(
            Pbuf, 1024, 1024 * 1024, VT, 1024, 256 * 1024, obufb, LDAP, 0,
            nullptr, 0, nullptr, nullptr, HDIM, 1024, nullptr, nullptr, nullptr);
        // h += o @ wo + bo
        gemm2_k<2, false, 0><<<dim3(11, 16, 1), 512, 0, stream>>>(
            obufb, LDAP, 0, woT, LDAP, 0, h, DMODEL, 0,
            bo + l * DMODEL, 0, nullptr, nullptr, DMODEL, LDAP, nullptr, nullptr, nullptr);

        // fused: tconv(w1) || tconv(w2) || LN2  (overwrites scores/Pbuf union; both dead)
        prep2_k<<<44 * 85 * 4 + 86 * 43 * 4 + 1024, 256, 0, stream>>>(
            w1_l, w2_l, w1T, w2T, h, ln2_g + l * DMODEL, ln2_b + l * DMODEL, lnA);
        // hid = relu(gather(lnA) @ w1[e] + b1[e]) -> bf16
        gemm2_k<1, true, 0><<<dim3(22, 16, 4), 512, 0, stream>>>(
            lnA, LDAP, 0, w1T, LDAP, (long long)2816 * LDAP,
            hid, KP2, (long long)1024 * KP2,
            b1 + (long long)l * 4 * DFFN, DFFN, perm, pcnt, DFFN, LDAP,
            nullptr, nullptr, nullptr);
        // h[tok] += hid @ w2[e] + b2[e]
        gemm2_k<3, false, 0><<<dim3(11, 16, 4), 512, 0, stream>>>(
            hid, KP2, (long long)1024 * KP2, w2T, KP2, (long long)1408 * KP2,
            h, DMODEL, 0,
            b2 + (long long)l * 4 * DMODEL, DMODEL, perm, pcnt, DMODEL, KP2,
            nullptr, nullptr, nullptr);
    }
}

// Round 17
// 1738.140 us; speedup vs baseline: 1.2820x; 1.0470x over previous
//
#include <hip/hip_runtime.h>
#include <hip/hip_bf16.h>
#include <cstdint>

#define S_LEN 1024
#define DMODEL 1352
#define TD 4056
#define DFFN 2704
#define NHEAD 8
#define HDIM 169
#define NLAYER 7
#define LDAP 1408   // 1352 -> 22*64
#define KP2 2752    // 2704 -> 43*64
#define QS 1536     // 8 heads * 192
#define HP 192      // head dim padded to 3*64

typedef __attribute__((ext_vector_type(8))) short short8;
typedef __attribute__((ext_vector_type(4))) float f32x4;
typedef __attribute__((ext_vector_type(2))) unsigned short us2;
typedef __attribute__((ext_vector_type(4))) unsigned short us4;

__device__ __forceinline__ unsigned short f2bf(float f) {
    union { float f; unsigned int u; } c; c.f = f;
    unsigned int r = (c.u + 0x7fffu + ((c.u >> 16) & 1u)) >> 16;
    return (unsigned short)r;
}

__device__ __forceinline__ void g2l16(const void* g, void* l) {
    __builtin_amdgcn_global_load_lds((__attribute__((address_space(1))) void*)g,
                                     (__attribute__((address_space(3))) void*)l,
                                     16, 0, 0);
}

// ---------------- routing ----------------
__global__ __launch_bounds__(256) void route_k(const float* __restrict__ x,
                                               int* __restrict__ perm,
                                               int* __restrict__ pcnt) {
    const int tid = threadIdx.x;
    const int lane = tid & 63;
    const int w = tid >> 6;
    for (int i = tid; i < 4096; i += 256) perm[i] = -1;
    __syncthreads();
    int base = 0;
    for (int c = 0; c < 16; ++c) {
        const int t = c * 64 + lane;
        const float* xr = x + (long long)t * DMODEL;
        float best = xr[0]; int bi = 0;
        #pragma unroll
        for (int j = 1; j < 16; ++j) { float v = xr[j]; if (v > best) { best = v; bi = j; } }
        const bool match = ((bi & 3) == w);
        unsigned long long mb = __ballot(match);
        int pos = __popcll(mb & ((1ull << lane) - 1ull));
        if (match) perm[w * 1024 + base + pos] = t;
        base += __popcll(mb);
    }
    if (lane == 0) pcnt[w] = (base + 127) & ~127;
}

// ---------------- r11 tconv tile (proven): 32x32, [32][33] LDS ----------------
__device__ __forceinline__ void tconv_tile(const float* __restrict__ src,
    unsigned short* __restrict__ dst, int K, int N, int Kp, int kt, int nt,
    float (*t)[33])
{
    const int k0 = kt * 32, n0 = nt * 32;
    const int tx = threadIdx.x & 31, ty = threadIdx.x >> 5;
    #pragma unroll
    for (int i = 0; i < 4; ++i) {
        int k = k0 + ty + i * 8, n = n0 + tx;
        t[ty + i * 8][tx] = (k < K && n < N) ? src[(long long)k * N + n] : 0.f;
    }
    __syncthreads();
    #pragma unroll
    for (int i = 0; i < 2; ++i) {
        int s = threadIdx.x + i * 256;
        int nr = s >> 4;
        int kp = (s & 15) * 2;
        int n = n0 + nr;
        if (n < N) {
            us2 w; w.x = f2bf(t[kp][nr]); w.y = f2bf(t[kp + 1][nr]);
            *(us2*)&dst[(long long)n * Kp + k0 + kp] = w;
        }
    }
}

__device__ __forceinline__ void ln_row(const float* __restrict__ h,
    const float* __restrict__ g, const float* __restrict__ b,
    unsigned short* __restrict__ out, int row, float* sA, float* sB)
{
    const float* hr = h + (long long)row * DMODEL;
    float s = 0.f, s2 = 0.f;
    for (int j = threadIdx.x; j < DMODEL; j += 256) { float v = hr[j]; s += v; s2 += v * v; }
    #pragma unroll
    for (int o = 32; o; o >>= 1) { s += __shfl_xor(s, o, 64); s2 += __shfl_xor(s2, o, 64); }
    const int lane = threadIdx.x & 63, wid = threadIdx.x >> 6;
    if (lane == 0) { sA[wid] = s; sB[wid] = s2; }
    __syncthreads();
    s = sA[0] + sA[1] + sA[2] + sA[3];
    s2 = sB[0] + sB[1] + sB[2] + sB[3];
    const float mu = s / DMODEL;
    const float rstd = rsqrtf(fmaxf(s2 / DMODEL - mu * mu, 0.f) + 1e-5f);
    unsigned short* orow = out + (long long)row * LDAP;
    for (int j = threadIdx.x; j < LDAP; j += 256) {
        float v = (j < DMODEL) ? (hr[j] - mu) * rstd * g[j] + b[j] : 0.f;
        orow[j] = f2bf(v);
    }
}

// ---------------- prep1: tconv(wqkv) || tconv(wo) || LN1 ----------------
__global__ __launch_bounds__(256) void prep1_k(
    const float* __restrict__ wqkv_l, const float* __restrict__ wo_l,
    unsigned short* __restrict__ wqkvT, unsigned short* __restrict__ woT,
    const float* __restrict__ h, const float* __restrict__ g,
    const float* __restrict__ bb, unsigned short* __restrict__ lnA)
{
    __shared__ __align__(16) float t[32][33];
    __shared__ float sA[4], sB[4];
    const int b = blockIdx.x;
    if (b < 44 * 127) {
        tconv_tile(wqkv_l, wqkvT, DMODEL, TD, LDAP, b % 44, b / 44, t);
    } else if (b < 44 * 127 + 44 * 43) {
        const int c = b - 44 * 127;
        tconv_tile(wo_l, woT, DMODEL, DMODEL, LDAP, c % 44, c / 44, t);
    } else {
        ln_row(h, g, bb, lnA, b - (44 * 127 + 44 * 43), sA, sB);
    }
}

// ---------------- prep2: tconv(w1) || tconv(w2) || LN2 ------------------
__global__ __launch_bounds__(256) void prep2_k(
    const float* __restrict__ w1_l, const float* __restrict__ w2_l,
    unsigned short* __restrict__ w1T, unsigned short* __restrict__ w2T,
    const float* __restrict__ h, const float* __restrict__ g,
    const float* __restrict__ bb, unsigned short* __restrict__ lnA)
{
    __shared__ __align__(16) float t[32][33];
    __shared__ float sA[4], sB[4];
    const int b = blockIdx.x;
    if (b < 44 * 85 * 4) {
        const int kt = b % 44, rem = b / 44;
        const int nt = rem % 85, z = rem / 85;
        tconv_tile(w1_l + (long long)z * DMODEL * DFFN,
                   w1T + (long long)z * 2816 * LDAP,
                   DMODEL, DFFN, LDAP, kt, nt, t);
    } else if (b < 44 * 85 * 4 + 86 * 43 * 4) {
        const int c = b - 44 * 85 * 4;
        const int kt = c % 86, rem = c / 86;
        const int nt = rem % 43, z = rem / 43;
        tconv_tile(w2_l + (long long)z * DFFN * DMODEL,
                   w2T + (long long)z * 1408 * KP2,
                   DFFN, DMODEL, KP2, kt, nt, t);
    } else {
        ln_row(h, g, bb, lnA, b - (44 * 85 * 4 + 86 * 43 * 4), sA, sB);
    }
}

// ---------------- causal row softmax (scores f32 -> P bf16) ----------------
__global__ __launch_bounds__(256) void softmax_k(const float* __restrict__ scores,
                                                 unsigned short* __restrict__ P,
                                                 float scale) {
    const int i = blockIdx.x;
    const long long rb = ((long long)blockIdx.y * 1024 + i) * 1024;
    const float* srow = scores + rb;
    unsigned short* prow = P + rb;
    const int n = i + 1;
    float mx = -3.4e38f;
    for (int j = threadIdx.x; j < n; j += 256) mx = fmaxf(mx, srow[j]);
    __shared__ float sA[4], sB[4];
    #pragma unroll
    for (int o = 32; o; o >>= 1) mx = fmaxf(mx, __shfl_xor(mx, o, 64));
    const int lane = threadIdx.x & 63, wid = threadIdx.x >> 6;
    if (lane == 0) sA[wid] = mx;
    __syncthreads();
    mx = fmaxf(fmaxf(sA[0], sA[1]), fmaxf(sA[2], sA[3])) * scale;
    float sum = 0.f;
    for (int j = threadIdx.x; j < n; j += 256) sum += __expf(srow[j] * scale - mx);
    #pragma unroll
    for (int o = 32; o; o >>= 1) sum += __shfl_xor(sum, o, 64);
    if (lane == 0) sB[wid] = sum;
    __syncthreads();
    const float inv = 1.f / (sB[0] + sB[1] + sB[2] + sB[3]);
    const int nz = ((i >> 7) + 1) << 7;
    for (int j = threadIdx.x; j < nz; j += 256) {
        float p = (j < n) ? __expf(srow[j] * scale - mx) * inv : 0.f;
        prow[j] = f2bf(p);
    }
}

// ---------------- pipelined bf16 MFMA GEMM, 64x128x64, 8 waves ----------------
// OCCUPANCY: 2 LDS buffers (48 KB) -> 3 blocks/CU, 6 waves/SIMD.
// 2-buffer schedule: {vmcnt(3)+barrier -> ds_read+MFMA -> barrier -> issue t+2
// into buf t%2}. Barrier-2 guarantees every wave's ds_reads of buf t%2 retired
// (compiler lgkmcnt before each consuming MFMA) before the refill is issued.
// In-order vmcnt retirement: at iter t+2's vmcnt(3), tile t+2's (older) loads
// are forced complete while tile t+3's 3 newest stay in flight.
// Swizzle as r14/r16: 16B slot s of row r at physical s^(r&7), both sides.
template<int EPI, bool GATHER, int CAUSAL>
__global__ __launch_bounds__(512) void gemm2_k(
    const unsigned short* __restrict__ A_, int lda, long long zsA,
    const unsigned short* __restrict__ B_, int ldb, long long zsB,
    void* __restrict__ C_, int ldc, long long zsC,
    const float* __restrict__ bias_, long long zsBias,
    const int* __restrict__ perm_, const int* __restrict__ pcnt,
    int N, int Kp,
    unsigned short* __restrict__ q_, unsigned short* __restrict__ k_,
    unsigned short* __restrict__ vt_) {
    const int z = blockIdx.z;
    const int gm0 = blockIdx.y * 64;
    const int n0 = blockIdx.x * 128;
    if (pcnt && gm0 >= pcnt[z]) return;
    if (CAUSAL == 1 && n0 >= gm0 + 64) return;

    const unsigned short* A = A_ + (long long)z * zsA;
    const unsigned short* B = B_ + (long long)z * zsB;
    const float* bias = bias_ ? bias_ + (long long)z * zsBias : nullptr;
    const int* perm = perm_ ? perm_ + (long long)z * 1024 : nullptr;

    __shared__ unsigned short Al[2][64 * 64];    // 16 KB
    __shared__ unsigned short Bl[2][128 * 64];   // 32 KB

    const int tid = threadIdx.x, lane = tid & 63, wid = tid >> 6;   // wid 0..7
    const int wr = wid >> 2, wc = wid & 3;                          // 2M x 4N waves
    const int l15 = lane & 15, lg = lane >> 4;

    const int sr = lane >> 3;             // 0..7
    const int scs = (lane & 7) ^ sr;      // pre-swizzled global 16B-slot

    // A staging: wave wid stages rows wid*8..+7 (1 load)
    const unsigned short* gA;
    {
        const int row = wid * 8 + sr;
        int ar = gm0 + row;
        if (GATHER) { const int p = perm[ar]; ar = (p < 0) ? 0 : p; }
        gA = A + (long long)ar * lda + scs * 8;
    }
    // B staging: wave wid stages rows wid*16+j*8..+7 (2 loads)
    const unsigned short* gB[2];
    #pragma unroll
    for (int j = 0; j < 2; ++j)
        gB[j] = B + (long long)(n0 + wid * 16 + j * 8 + sr) * ldb + scs * 8;

    const int ldsA = wid * 512;           // elements
    const int ldsB = wid * 1024;

    int nt = Kp >> 6;
    if (CAUSAL == 2) { int ke = gm0 + 64; if (ke > Kp) ke = Kp; nt = ke >> 6; }

    f32x4 acc[2][2] = {};

    // prologue: issue tiles 0,1 (3 vmem ops per wave per tile; clamped)
    #pragma unroll
    for (int tt = 0; tt < 2; ++tt) {
        const int ts = (tt < nt) ? tt : nt - 1;
        const int ko = ts * 64;
        g2l16(gA + ko, &Al[tt & 1][ldsA]);
        g2l16(gB[0] + ko, &Bl[tt & 1][ldsB]);
        g2l16(gB[1] + ko, &Bl[tt & 1][ldsB + 512]);
    }

    for (int t = 0; t < nt; ++t) {
        // 3 newest loads = tile t+1 -> tile t resident after this wait
        asm volatile("s_waitcnt vmcnt(3)" ::: "memory");
        __builtin_amdgcn_s_barrier();
        __builtin_amdgcn_sched_barrier(0);
        const int cur = t & 1;
        short8 af[2][2], bfv[2][2];
        #pragma unroll
        for (int m = 0; m < 2; ++m)
            #pragma unroll
            for (int s = 0; s < 2; ++s)
                af[m][s] = *(const short8*)&Al[cur][(wr * 32 + m * 16 + l15) * 64 +
                                                    (((s * 4 + lg) ^ (l15 & 7)) * 8)];
        #pragma unroll
        for (int n = 0; n < 2; ++n)
            #pragma unroll
            for (int s = 0; s < 2; ++s)
                bfv[n][s] = *(const short8*)&Bl[cur][(wc * 32 + n * 16 + l15) * 64 +
                                                     (((s * 4 + lg) ^ (l15 & 7)) * 8)];
        #pragma unroll
        for (int s = 0; s < 2; ++s)
            #pragma unroll
            for (int m = 0; m < 2; ++m)
                #pragma unroll
                for (int n = 0; n < 2; ++n)
                    acc[m][n] = __builtin_amdgcn_mfma_f32_16x16x32_bf16(af[m][s], bfv[n][s], acc[m][n], 0, 0, 0);
        // all waves' ds_reads of buf cur retired once every wave reaches here
        __builtin_amdgcn_sched_barrier(0);
        __builtin_amdgcn_s_barrier();
        __builtin_amdgcn_sched_barrier(0);
        // refill buf cur with tile t+2 (clamped dummy keeps vmcnt uniform)
        {
            const int ts = (t + 2 < nt) ? t + 2 : nt - 1;
            const int ko = ts * 64;
            g2l16(gA + ko, &Al[cur][ldsA]);
            g2l16(gB[0] + ko, &Bl[cur][ldsB]);
            g2l16(gB[1] + ko, &Bl[cur][ldsB + 512]);
        }
    }

    // DRAIN: no LDS-DMA may be in flight at s_endpgm (round-3 race)
    asm volatile("s_waitcnt vmcnt(0) lgkmcnt(0)" ::: "memory");

    const int lq = lg * 4;
    #pragma unroll
    for (int m = 0; m < 2; ++m) {
        const int trow = wr * 32 + m * 16 + lq;
        #pragma unroll
        for (int n = 0; n < 2; ++n) {
            const int col = n0 + wc * 32 + n * 16 + l15;
            if (col >= N) continue;
            const float bv = bias ? bias[col] : 0.f;
            if (EPI == 5) {
                const int role = col / 1352;
                const int within = col - role * 1352;
                const int hh = within / 169;
                const int dd = within - hh * 169;
                if (role == 2) {
                    us4 pk;
                    #pragma unroll
                    for (int r = 0; r < 4; ++r) pk[r] = f2bf(acc[m][n][r] + bv);
                    *(us4*)&vt_[(long long)(hh * 256 + dd) * 1024 + gm0 + trow] = pk;
                } else {
                    unsigned short* dstb = role ? k_ : q_;
                    #pragma unroll
                    for (int r = 0; r < 4; ++r)
                        dstb[(long long)(gm0 + trow + r) * QS + hh * HP + dd] =
                            f2bf(acc[m][n][r] + bv);
                }
            } else {
                #pragma unroll
                for (int r = 0; r < 4; ++r) {
                    const int grow = gm0 + trow + r;
                    const float v = acc[m][n][r] + bv;
                    if (EPI == 0) {
                        ((float*)C_)[(long long)z * zsC + (long long)grow * ldc + col] = v;
                    } else if (EPI == 1) {
                        const int tok = perm[grow];
                        ((unsigned short*)C_)[(long long)z * zsC + (long long)grow * ldc + col] =
                            (tok >= 0) ? f2bf(fmaxf(v, 0.f)) : (unsigned short)0;
                    } else if (EPI == 2) {
                        ((float*)C_)[(long long)grow * ldc + col] += v;
                    } else if (EPI == 3) {
                        const int tok = perm[grow];
                        if (tok >= 0) ((float*)C_)[(long long)tok * ldc + col] += v;
                    } else if (EPI == 6) {
                        ((unsigned short*)C_)[(long long)grow * ldc + z * 169 + col] = f2bf(v);
                    }
                }
            }
        }
    }
}

extern "C" void kernel_launch(void* const* d_in, const int* in_sizes, int n_in,
                              void* d_out, int out_size, void* d_ws, size_t ws_size,
                              hipStream_t stream) {
    const float* x     = (const float*)d_in[0];
    const float* ln1_g = (const float*)d_in[1];
    const float* ln1_b = (const float*)d_in[2];
    const float* wqkv  = (const float*)d_in[3];
    const float* bqkv  = (const float*)d_in[4];
    const float* wo    = (const float*)d_in[5];
    const float* bo    = (const float*)d_in[6];
    const float* ln2_g = (const float*)d_in[7];
    const float* ln2_b = (const float*)d_in[8];
    const float* w1    = (const float*)d_in[9];
    const float* b1    = (const float*)d_in[10];
    const float* w2    = (const float*)d_in[11];
    const float* b2    = (const float*)d_in[12];

    float* h = (float*)d_out;

    char* w = (char*)d_ws;
    auto alloc = [&](size_t bytes) { void* p = w; w += (bytes + 255) & ~255ull; return p; };
    unsigned short* lnA   = (unsigned short*)alloc((size_t)S_LEN * LDAP * 2);
    unsigned short* qb    = (unsigned short*)alloc((size_t)S_LEN * QS * 2);
    unsigned short* kb    = (unsigned short*)alloc((size_t)S_LEN * QS * 2);
    unsigned short* VT    = (unsigned short*)alloc((size_t)NHEAD * 256 * 1024 * 2);
    unsigned short* obufb = (unsigned short*)alloc((size_t)S_LEN * LDAP * 2);
    unsigned short* hid   = (unsigned short*)alloc((size_t)4096 * KP2 * 2);
    unsigned short* wqkvT = (unsigned short*)alloc((size_t)4096 * LDAP * 2);
    unsigned short* woT   = (unsigned short*)alloc((size_t)1408 * LDAP * 2);
    char*           U     = (char*)alloc((size_t)64000000);   // union (time-aliased, L3-hot)
    int* perm = (int*)alloc(4096 * 4);
    int* pcnt = (int*)alloc(64);

    float*          scores = (float*)U;
    unsigned short* Pbuf   = (unsigned short*)(U + (size_t)NHEAD * 1024 * 1024 * 4);
    unsigned short* w1T    = (unsigned short*)U;
    unsigned short* w2T    = (unsigned short*)(U + (size_t)4 * 2816 * LDAP * 2);

    hipMemcpyAsync(h, x, (size_t)S_LEN * DMODEL * 4, hipMemcpyDeviceToDevice, stream);
    // q/k head-pad slots enter the scores MFMA -> must be zero
    hipMemsetAsync(qb, 0, (size_t)S_LEN * QS * 2, stream);
    hipMemsetAsync(kb, 0, (size_t)S_LEN * QS * 2, stream);
    route_k<<<1, 256, 0, stream>>>(x, perm, pcnt);

    const float scale = 1.0f / 13.0f;

    for (int l = 0; l < NLAYER; ++l) {
        const float* wqkv_l = wqkv + (long long)l * DMODEL * TD;
        const float* wo_l   = wo   + (long long)l * DMODEL * DMODEL;
        const float* w1_l   = w1   + (long long)l * 4 * DMODEL * DFFN;
        const float* w2_l   = w2   + (long long)l * 4 * DFFN * DMODEL;

        // fused: tconv(wqkv) || tconv(wo) || LN1
        prep1_k<<<44 * 127 + 44 * 43 + 1024, 256, 0, stream>>>(
            wqkv_l, wo_l, wqkvT, woT, h, ln1_g + l * DMODEL, ln1_b + l * DMODEL, lnA);
        // QKV -> split bf16 q/k (head-padded) + V transposed
        gemm2_k<5, false, 0><<<dim3(32, 16, 1), 512, 0, stream>>>(
            lnA, LDAP, 0, wqkvT, LDAP, 0, nullptr, 0, 0,
            bqkv + l * TD, 0, nullptr, nullptr, TD, LDAP, qb, kb, VT);
        // scores = q @ k^T per head (causal tiles only)
        gemm2_k<0, false, 1><<<dim3(8, 16, 8), 512, 0, stream>>>(
            qb, QS, HP, kb, QS, HP, scores, 1024, 1024 * 1024,
            nullptr, 0, nullptr, nullptr, 1024, HP, nullptr, nullptr, nullptr);
        softmax_k<<<dim3(1024, NHEAD), 256, 0, stream>>>(scores, Pbuf, scale);
        // o = P @ v per head -> compact bf16 [1024][1408]
        gemm2_k<6, false, 2><<<dim3(2, 16, 8), 512, 0, stream>>>(
            Pbuf, 1024, 1024 * 1024, VT, 1024, 256 * 1024, obufb, LDAP, 0,
            nullptr, 0, nullptr, nullptr, HDIM, 1024, nullptr, nullptr, nullptr);
        // h += o @ wo + bo
        gemm2_k<2, false, 0><<<dim3(11, 16, 1), 512, 0, stream>>>(
            obufb, LDAP, 0, woT, LDAP, 0, h, DMODEL, 0,
            bo + l * DMODEL, 0, nullptr, nullptr, DMODEL, LDAP, nullptr, nullptr, nullptr);

        // fused: tconv(w1) || tconv(w2) || LN2  (overwrites scores/Pbuf union; both dead)
        prep2_k<<<44 * 85 * 4 + 86 * 43 * 4 + 1024, 256, 0, stream>>>(
            w1_l, w2_l, w1T, w2T, h, ln2_g + l * DMODEL, ln2_b + l * DMODEL, lnA);
        // hid = relu(gather(lnA) @ w1[e] + b1[e]) -> bf16
        gemm2_k<1, true, 0><<<dim3(22, 16, 4), 512, 0, stream>>>(
            lnA, LDAP, 0, w1T, LDAP, (long long)2816 * LDAP,
            hid, KP2, (long long)1024 * KP2,
            b1 + (long long)l * 4 * DFFN, DFFN, perm, pcnt, DFFN, LDAP,
            nullptr, nullptr, nullptr);
        // h[tok] += hid @ w2[e] + b2[e]
        gemm2_k<3, false, 0><<<dim3(11, 16, 4), 512, 0, stream>>>(
            hid, KP2, (long long)1024 * KP2, w2T, KP2, (long long)1408 * KP2,
            h, DMODEL, 0,
            b2 + (long long)l * 4 * DMODEL, DMODEL, perm, pcnt, DMODEL, KP2,
            nullptr, nullptr, nullptr);
    }
}

// Round 18
// 1652.630 us; speedup vs baseline: 1.3483x; 1.0517x over previous
//
#include <hip/hip_runtime.h>
#include <hip/hip_bf16.h>
#include <cstdint>

#define S_LEN 1024
#define DMODEL 1352
#define TD 4056
#define DFFN 2704
#define NHEAD 8
#define HDIM 169
#define NLAYER 7
#define LDAP 1408   // 1352 -> 22*64
#define KP2 2752    // 2704 -> 43*64
#define QS 1536     // 8 heads * 192
#define HP 192      // head dim padded to 3*64

typedef __attribute__((ext_vector_type(8))) short short8;
typedef __attribute__((ext_vector_type(4))) float f32x4;
typedef __attribute__((ext_vector_type(2))) unsigned short us2;
typedef __attribute__((ext_vector_type(4))) unsigned short us4;

__device__ __forceinline__ unsigned short f2bf(float f) {
    union { float f; unsigned int u; } c; c.f = f;
    unsigned int r = (c.u + 0x7fffu + ((c.u >> 16) & 1u)) >> 16;
    return (unsigned short)r;
}

__device__ __forceinline__ void g2l16(const void* g, void* l) {
    __builtin_amdgcn_global_load_lds((__attribute__((address_space(1))) void*)g,
                                     (__attribute__((address_space(3))) void*)l,
                                     16, 0, 0);
}

// ---------------- routing ----------------
__global__ __launch_bounds__(256) void route_k(const float* __restrict__ x,
                                               int* __restrict__ perm,
                                               int* __restrict__ pcnt) {
    const int tid = threadIdx.x;
    const int lane = tid & 63;
    const int w = tid >> 6;
    for (int i = tid; i < 4096; i += 256) perm[i] = -1;
    __syncthreads();
    int base = 0;
    for (int c = 0; c < 16; ++c) {
        const int t = c * 64 + lane;
        const float* xr = x + (long long)t * DMODEL;
        float best = xr[0]; int bi = 0;
        #pragma unroll
        for (int j = 1; j < 16; ++j) { float v = xr[j]; if (v > best) { best = v; bi = j; } }
        const bool match = ((bi & 3) == w);
        unsigned long long mb = __ballot(match);
        int pos = __popcll(mb & ((1ull << lane) - 1ull));
        if (match) perm[w * 1024 + base + pos] = t;
        base += __popcll(mb);
    }
    if (lane == 0) pcnt[w] = (base + 127) & ~127;
}

// ---------------- tconv tile 32k x 64n: full 256B coalesced row reads ----------
// Read: wave wv reads rows wv*8..+7, each row = 64 consecutive floats (256B).
// Write: r11-proven pattern, 64B-contiguous us2 stores per dst row (4 passes).
// LDS [32][65] f32: write banks (r*65+lane)%32 -> 2-way (free); read phase
// (2j+nr)%32 spread over all banks.
__device__ __forceinline__ void tconv_tile64(const float* __restrict__ src,
    unsigned short* __restrict__ dst, int K, int N, int Kp, int kt, int nt,
    float (*t)[65])
{
    const int k0 = kt * 32, n0 = nt * 64;
    const int lane = threadIdx.x & 63, wv = threadIdx.x >> 6;
    #pragma unroll
    for (int i = 0; i < 8; ++i) {
        const int k = k0 + wv * 8 + i;
        const int n = n0 + lane;
        t[wv * 8 + i][lane] = (k < K && n < N) ? src[(long long)k * N + n] : 0.f;
    }
    __syncthreads();
    #pragma unroll
    for (int p = 0; p < 4; ++p) {
        const int nr = p * 16 + (threadIdx.x >> 4);   // 0..63
        const int kp = (threadIdx.x & 15) * 2;        // 0..30
        const int n = n0 + nr;
        if (n < N) {
            us2 wv2; wv2.x = f2bf(t[kp][nr]); wv2.y = f2bf(t[kp + 1][nr]);
            *(us2*)&dst[(long long)n * Kp + k0 + kp] = wv2;
        }
    }
}

__device__ __forceinline__ void ln_row(const float* __restrict__ h,
    const float* __restrict__ g, const float* __restrict__ b,
    unsigned short* __restrict__ out, int row, float* sA, float* sB)
{
    const float* hr = h + (long long)row * DMODEL;
    float s = 0.f, s2 = 0.f;
    for (int j = threadIdx.x; j < DMODEL; j += 256) { float v = hr[j]; s += v; s2 += v * v; }
    #pragma unroll
    for (int o = 32; o; o >>= 1) { s += __shfl_xor(s, o, 64); s2 += __shfl_xor(s2, o, 64); }
    const int lane = threadIdx.x & 63, wid = threadIdx.x >> 6;
    if (lane == 0) { sA[wid] = s; sB[wid] = s2; }
    __syncthreads();
    s = sA[0] + sA[1] + sA[2] + sA[3];
    s2 = sB[0] + sB[1] + sB[2] + sB[3];
    const float mu = s / DMODEL;
    const float rstd = rsqrtf(fmaxf(s2 / DMODEL - mu * mu, 0.f) + 1e-5f);
    unsigned short* orow = out + (long long)row * LDAP;
    for (int j = threadIdx.x; j < LDAP; j += 256) {
        float v = (j < DMODEL) ? (hr[j] - mu) * rstd * g[j] + b[j] : 0.f;
        orow[j] = f2bf(v);
    }
}

#define NB1_QKV (44 * 64)
#define NB1_WO  (44 * 22)
#define NB2_W1  (44 * 43 * 4)
#define NB2_W2  (86 * 22 * 4)

// ---------------- prep1: tconv(wqkv) || tconv(wo) || LN1 ----------------
__global__ __launch_bounds__(256) void prep1_k(
    const float* __restrict__ wqkv_l, const float* __restrict__ wo_l,
    unsigned short* __restrict__ wqkvT, unsigned short* __restrict__ woT,
    const float* __restrict__ h, const float* __restrict__ g,
    const float* __restrict__ bb, unsigned short* __restrict__ lnA)
{
    __shared__ __align__(16) float t[32][65];
    __shared__ float sA[4], sB[4];
    int b = blockIdx.x;
    if (b < NB1_QKV) {
        tconv_tile64(wqkv_l, wqkvT, DMODEL, TD, LDAP, b % 44, b / 44, t);
        return;
    }
    b -= NB1_QKV;
    if (b < NB1_WO) {
        tconv_tile64(wo_l, woT, DMODEL, DMODEL, LDAP, b % 44, b / 44, t);
        return;
    }
    b -= NB1_WO;
    ln_row(h, g, bb, lnA, b, sA, sB);
}

// ---------------- prep2: tconv(w1) || tconv(w2) || LN2 ------------------
__global__ __launch_bounds__(256) void prep2_k(
    const float* __restrict__ w1_l, const float* __restrict__ w2_l,
    unsigned short* __restrict__ w1T, unsigned short* __restrict__ w2T,
    const float* __restrict__ h, const float* __restrict__ g,
    const float* __restrict__ bb, unsigned short* __restrict__ lnA)
{
    __shared__ __align__(16) float t[32][65];
    __shared__ float sA[4], sB[4];
    int b = blockIdx.x;
    if (b < NB2_W1) {
        const int kt = b % 44, rem = b / 44;
        const int nt = rem % 43, z = rem / 43;
        tconv_tile64(w1_l + (long long)z * DMODEL * DFFN,
                     w1T + (long long)z * 2816 * LDAP,
                     DMODEL, DFFN, LDAP, kt, nt, t);
        return;
    }
    b -= NB2_W1;
    if (b < NB2_W2) {
        const int kt = b % 86, rem = b / 86;
        const int nt = rem % 22, z = rem / 22;
        tconv_tile64(w2_l + (long long)z * DFFN * DMODEL,
                     w2T + (long long)z * 1408 * KP2,
                     DFFN, DMODEL, KP2, kt, nt, t);
        return;
    }
    b -= NB2_W2;
    ln_row(h, g, bb, lnA, b, sA, sB);
}

// ---------------- causal row softmax (scores f32 -> P bf16) ----------------
__global__ __launch_bounds__(256) void softmax_k(const float* __restrict__ scores,
                                                 unsigned short* __restrict__ P,
                                                 float scale) {
    const int i = blockIdx.x;
    const long long rb = ((long long)blockIdx.y * 1024 + i) * 1024;
    const float* srow = scores + rb;
    unsigned short* prow = P + rb;
    const int n = i + 1;
    float mx = -3.4e38f;
    for (int j = threadIdx.x; j < n; j += 256) mx = fmaxf(mx, srow[j]);
    __shared__ float sA[4], sB[4];
    #pragma unroll
    for (int o = 32; o; o >>= 1) mx = fmaxf(mx, __shfl_xor(mx, o, 64));
    const int lane = threadIdx.x & 63, wid = threadIdx.x >> 6;
    if (lane == 0) sA[wid] = mx;
    __syncthreads();
    mx = fmaxf(fmaxf(sA[0], sA[1]), fmaxf(sA[2], sA[3])) * scale;
    float sum = 0.f;
    for (int j = threadIdx.x; j < n; j += 256) sum += __expf(srow[j] * scale - mx);
    #pragma unroll
    for (int o = 32; o; o >>= 1) sum += __shfl_xor(sum, o, 64);
    if (lane == 0) sB[wid] = sum;
    __syncthreads();
    const float inv = 1.f / (sB[0] + sB[1] + sB[2] + sB[3]);
    const int nz = ((i >> 7) + 1) << 7;
    for (int j = threadIdx.x; j < nz; j += 256) {
        float p = (j < n) ? __expf(srow[j] * scale - mx) * inv : 0.f;
        prow[j] = f2bf(p);
    }
}

// ---------------- pipelined bf16 MFMA GEMM, 64x128x64, 8 waves (r17) ----------
template<int EPI, bool GATHER, int CAUSAL>
__global__ __launch_bounds__(512) void gemm2_k(
    const unsigned short* __restrict__ A_, int lda, long long zsA,
    const unsigned short* __restrict__ B_, int ldb, long long zsB,
    void* __restrict__ C_, int ldc, long long zsC,
    const float* __restrict__ bias_, long long zsBias,
    const int* __restrict__ perm_, const int* __restrict__ pcnt,
    int N, int Kp,
    unsigned short* __restrict__ q_, unsigned short* __restrict__ k_,
    unsigned short* __restrict__ vt_) {
    const int z = blockIdx.z;
    const int gm0 = blockIdx.y * 64;
    const int n0 = blockIdx.x * 128;
    if (pcnt && gm0 >= pcnt[z]) return;
    if (CAUSAL == 1 && n0 >= gm0 + 64) return;

    const unsigned short* A = A_ + (long long)z * zsA;
    const unsigned short* B = B_ + (long long)z * zsB;
    const float* bias = bias_ ? bias_ + (long long)z * zsBias : nullptr;
    const int* perm = perm_ ? perm_ + (long long)z * 1024 : nullptr;

    __shared__ unsigned short Al[2][64 * 64];    // 16 KB
    __shared__ unsigned short Bl[2][128 * 64];   // 32 KB

    const int tid = threadIdx.x, lane = tid & 63, wid = tid >> 6;   // wid 0..7
    const int wr = wid >> 2, wc = wid & 3;                          // 2M x 4N waves
    const int l15 = lane & 15, lg = lane >> 4;

    const int sr = lane >> 3;             // 0..7
    const int scs = (lane & 7) ^ sr;      // pre-swizzled global 16B-slot

    const unsigned short* gA;
    {
        const int row = wid * 8 + sr;
        int ar = gm0 + row;
        if (GATHER) { const int p = perm[ar]; ar = (p < 0) ? 0 : p; }
        gA = A + (long long)ar * lda + scs * 8;
    }
    const unsigned short* gB[2];
    #pragma unroll
    for (int j = 0; j < 2; ++j)
        gB[j] = B + (long long)(n0 + wid * 16 + j * 8 + sr) * ldb + scs * 8;

    const int ldsA = wid * 512;
    const int ldsB = wid * 1024;

    int nt = Kp >> 6;
    if (CAUSAL == 2) { int ke = gm0 + 64; if (ke > Kp) ke = Kp; nt = ke >> 6; }

    f32x4 acc[2][2] = {};

    #pragma unroll
    for (int tt = 0; tt < 2; ++tt) {
        const int ts = (tt < nt) ? tt : nt - 1;
        const int ko = ts * 64;
        g2l16(gA + ko, &Al[tt & 1][ldsA]);
        g2l16(gB[0] + ko, &Bl[tt & 1][ldsB]);
        g2l16(gB[1] + ko, &Bl[tt & 1][ldsB + 512]);
    }

    for (int t = 0; t < nt; ++t) {
        asm volatile("s_waitcnt vmcnt(3)" ::: "memory");
        __builtin_amdgcn_s_barrier();
        __builtin_amdgcn_sched_barrier(0);
        const int cur = t & 1;
        short8 af[2][2], bfv[2][2];
        #pragma unroll
        for (int m = 0; m < 2; ++m)
            #pragma unroll
            for (int s = 0; s < 2; ++s)
                af[m][s] = *(const short8*)&Al[cur][(wr * 32 + m * 16 + l15) * 64 +
                                                    (((s * 4 + lg) ^ (l15 & 7)) * 8)];
        #pragma unroll
        for (int n = 0; n < 2; ++n)
            #pragma unroll
            for (int s = 0; s < 2; ++s)
                bfv[n][s] = *(const short8*)&Bl[cur][(wc * 32 + n * 16 + l15) * 64 +
                                                     (((s * 4 + lg) ^ (l15 & 7)) * 8)];
        #pragma unroll
        for (int s = 0; s < 2; ++s)
            #pragma unroll
            for (int m = 0; m < 2; ++m)
                #pragma unroll
                for (int n = 0; n < 2; ++n)
                    acc[m][n] = __builtin_amdgcn_mfma_f32_16x16x32_bf16(af[m][s], bfv[n][s], acc[m][n], 0, 0, 0);
        __builtin_amdgcn_sched_barrier(0);
        __builtin_amdgcn_s_barrier();
        __builtin_amdgcn_sched_barrier(0);
        {
            const int ts = (t + 2 < nt) ? t + 2 : nt - 1;
            const int ko = ts * 64;
            g2l16(gA + ko, &Al[cur][ldsA]);
            g2l16(gB[0] + ko, &Bl[cur][ldsB]);
            g2l16(gB[1] + ko, &Bl[cur][ldsB + 512]);
        }
    }

    // DRAIN: no LDS-DMA may be in flight at s_endpgm (round-3 race)
    asm volatile("s_waitcnt vmcnt(0) lgkmcnt(0)" ::: "memory");

    const int lq = lg * 4;
    #pragma unroll
    for (int m = 0; m < 2; ++m) {
        const int trow = wr * 32 + m * 16 + lq;
        #pragma unroll
        for (int n = 0; n < 2; ++n) {
            const int col = n0 + wc * 32 + n * 16 + l15;
            if (col >= N) continue;
            const float bv = bias ? bias[col] : 0.f;
            if (EPI == 5) {
                const int role = col / 1352;
                const int within = col - role * 1352;
                const int hh = within / 169;
                const int dd = within - hh * 169;
                if (role == 2) {
                    us4 pk;
                    #pragma unroll
                    for (int r = 0; r < 4; ++r) pk[r] = f2bf(acc[m][n][r] + bv);
                    *(us4*)&vt_[(long long)(hh * 256 + dd) * 1024 + gm0 + trow] = pk;
                } else {
                    unsigned short* dstb = role ? k_ : q_;
                    #pragma unroll
                    for (int r = 0; r < 4; ++r)
                        dstb[(long long)(gm0 + trow + r) * QS + hh * HP + dd] =
                            f2bf(acc[m][n][r] + bv);
                }
            } else {
                #pragma unroll
                for (int r = 0; r < 4; ++r) {
                    const int grow = gm0 + trow + r;
                    const float v = acc[m][n][r] + bv;
                    if (EPI == 0) {
                        ((float*)C_)[(long long)z * zsC + (long long)grow * ldc + col] = v;
                    } else if (EPI == 1) {
                        const int tok = perm[grow];
                        ((unsigned short*)C_)[(long long)z * zsC + (long long)grow * ldc + col] =
                            (tok >= 0) ? f2bf(fmaxf(v, 0.f)) : (unsigned short)0;
                    } else if (EPI == 2) {
                        ((float*)C_)[(long long)grow * ldc + col] += v;
                    } else if (EPI == 3) {
                        const int tok = perm[grow];
                        if (tok >= 0) ((float*)C_)[(long long)tok * ldc + col] += v;
                    } else if (EPI == 6) {
                        ((unsigned short*)C_)[(long long)grow * ldc + z * 169 + col] = f2bf(v);
                    }
                }
            }
        }
    }
}

extern "C" void kernel_launch(void* const* d_in, const int* in_sizes, int n_in,
                              void* d_out, int out_size, void* d_ws, size_t ws_size,
                              hipStream_t stream) {
    const float* x     = (const float*)d_in[0];
    const float* ln1_g = (const float*)d_in[1];
    const float* ln1_b = (const float*)d_in[2];
    const float* wqkv  = (const float*)d_in[3];
    const float* bqkv  = (const float*)d_in[4];
    const float* wo    = (const float*)d_in[5];
    const float* bo    = (const float*)d_in[6];
    const float* ln2_g = (const float*)d_in[7];
    const float* ln2_b = (const float*)d_in[8];
    const float* w1    = (const float*)d_in[9];
    const float* b1    = (const float*)d_in[10];
    const float* w2    = (const float*)d_in[11];
    const float* b2    = (const float*)d_in[12];

    float* h = (float*)d_out;

    char* w = (char*)d_ws;
    auto alloc = [&](size_t bytes) { void* p = w; w += (bytes + 255) & ~255ull; return p; };
    unsigned short* lnA   = (unsigned short*)alloc((size_t)S_LEN * LDAP * 2);
    unsigned short* qb    = (unsigned short*)alloc((size_t)S_LEN * QS * 2);
    unsigned short* kb    = (unsigned short*)alloc((size_t)S_LEN * QS * 2);
    unsigned short* VT    = (unsigned short*)alloc((size_t)NHEAD * 256 * 1024 * 2);
    unsigned short* obufb = (unsigned short*)alloc((size_t)S_LEN * LDAP * 2);
    unsigned short* hid   = (unsigned short*)alloc((size_t)4096 * KP2 * 2);
    unsigned short* wqkvT = (unsigned short*)alloc((size_t)4096 * LDAP * 2);
    unsigned short* woT   = (unsigned short*)alloc((size_t)1408 * LDAP * 2);
    char*           U     = (char*)alloc((size_t)64000000);   // union (time-aliased, L3-hot)
    int* perm = (int*)alloc(4096 * 4);
    int* pcnt = (int*)alloc(64);

    float*          scores = (float*)U;
    unsigned short* Pbuf   = (unsigned short*)(U + (size_t)NHEAD * 1024 * 1024 * 4);
    unsigned short* w1T    = (unsigned short*)U;
    unsigned short* w2T    = (unsigned short*)(U + (size_t)4 * 2816 * LDAP * 2);

    hipMemcpyAsync(h, x, (size_t)S_LEN * DMODEL * 4, hipMemcpyDeviceToDevice, stream);
    // q/k head-pad slots enter the scores MFMA -> must be zero
    hipMemsetAsync(qb, 0, (size_t)S_LEN * QS * 2, stream);
    hipMemsetAsync(kb, 0, (size_t)S_LEN * QS * 2, stream);
    route_k<<<1, 256, 0, stream>>>(x, perm, pcnt);

    const float scale = 1.0f / 13.0f;

    for (int l = 0; l < NLAYER; ++l) {
        const float* wqkv_l = wqkv + (long long)l * DMODEL * TD;
        const float* wo_l   = wo   + (long long)l * DMODEL * DMODEL;
        const float* w1_l   = w1   + (long long)l * 4 * DMODEL * DFFN;
        const float* w2_l   = w2   + (long long)l * 4 * DFFN * DMODEL;

        // fused: tconv(wqkv) || tconv(wo) || LN1
        prep1_k<<<NB1_QKV + NB1_WO + 1024, 256, 0, stream>>>(
            wqkv_l, wo_l, wqkvT, woT, h, ln1_g + l * DMODEL, ln1_b + l * DMODEL, lnA);
        // QKV -> split bf16 q/k (head-padded) + V transposed
        gemm2_k<5, false, 0><<<dim3(32, 16, 1), 512, 0, stream>>>(
            lnA, LDAP, 0, wqkvT, LDAP, 0, nullptr, 0, 0,
            bqkv + l * TD, 0, nullptr, nullptr, TD, LDAP, qb, kb, VT);
        // scores = q @ k^T per head (causal tiles only)
        gemm2_k<0, false, 1><<<dim3(8, 16, 8), 512, 0, stream>>>(
            qb, QS, HP, kb, QS, HP, scores, 1024, 1024 * 1024,
            nullptr, 0, nullptr, nullptr, 1024, HP, nullptr, nullptr, nullptr);
        softmax_k<<<dim3(1024, NHEAD), 256, 0, stream>>>(scores, Pbuf, scale);
        // o = P @ v per head -> compact bf16 [1024][1408]
        gemm2_k<6, false, 2><<<dim3(2, 16, 8), 512, 0, stream>>>(
            Pbuf, 1024, 1024 * 1024, VT, 1024, 256 * 1024, obufb, LDAP, 0,
            nullptr, 0, nullptr, nullptr, HDIM, 1024, nullptr, nullptr, nullptr);
        // h += o @ wo + bo
        gemm2_k<2, false, 0><<<dim3(11, 16, 1), 512, 0, stream>>>(
            obufb, LDAP, 0, woT, LDAP, 0, h, DMODEL, 0,
            bo + l * DMODEL, 0, nullptr, nullptr, DMODEL, LDAP, nullptr, nullptr, nullptr);

        // fused: tconv(w1) || tconv(w2) || LN2  (overwrites scores/Pbuf union; both dead)
        prep2_k<<<NB2_W1 + NB2_W2 + 1024, 256, 0, stream>>>(
            w1_l, w2_l, w1T, w2T, h, ln2_g + l * DMODEL, ln2_b + l * DMODEL, lnA);
        // hid = relu(gather(lnA) @ w1[e] + b1[e]) -> bf16
        gemm2_k<1, true, 0><<<dim3(22, 16, 4), 512, 0, stream>>>(
            lnA, LDAP, 0, w1T, LDAP, (long long)2816 * LDAP,
            hid, KP2, (long long)1024 * KP2,
            b1 + (long long)l * 4 * DFFN, DFFN, perm, pcnt, DFFN, LDAP,
            nullptr, nullptr, nullptr);
        // h[tok] += hid @ w2[e] + b2[e]
        gemm2_k<3, false, 0><<<dim3(11, 16, 4), 512, 0, stream>>>(
            hid, KP2, (long long)1024 * KP2, w2T, KP2, (long long)1408 * KP2,
            h, DMODEL, 0,
            b2 + (long long)l * 4 * DMODEL, DMODEL, perm, pcnt, DMODEL, KP2,
            nullptr, nullptr, nullptr);
    }
}

// Round 19
// 1605.181 us; speedup vs baseline: 1.3882x; 1.0296x over previous
//
#include <hip/hip_runtime.h>
#include <hip/hip_bf16.h>
#include <cstdint>

#define S_LEN 1024
#define DMODEL 1352
#define TD 4056
#define DFFN 2704
#define NHEAD 8
#define HDIM 169
#define NLAYER 7
#define LDAP 1408   // 1352 -> 22*64
#define KP2 2752    // 2704 -> 43*64
#define QS 1536     // 8 heads * 192
#define HP 192      // head dim padded to 3*64

typedef __attribute__((ext_vector_type(8))) short short8;
typedef __attribute__((ext_vector_type(4))) float f32x4;
typedef __attribute__((ext_vector_type(2))) unsigned short us2;
typedef __attribute__((ext_vector_type(4))) unsigned short us4;

__device__ __forceinline__ unsigned short f2bf(float f) {
    union { float f; unsigned int u; } c; c.f = f;
    unsigned int r = (c.u + 0x7fffu + ((c.u >> 16) & 1u)) >> 16;
    return (unsigned short)r;
}

__device__ __forceinline__ float bf2f(unsigned short u) {
    union { unsigned int u; float f; } c; c.u = (unsigned int)u << 16;
    return c.f;
}

__device__ __forceinline__ void g2l16(const void* g, void* l) {
    __builtin_amdgcn_global_load_lds((__attribute__((address_space(1))) void*)g,
                                     (__attribute__((address_space(3))) void*)l,
                                     16, 0, 0);
}

// ---------------- routing ----------------
__global__ __launch_bounds__(256) void route_k(const float* __restrict__ x,
                                               int* __restrict__ perm,
                                               int* __restrict__ pcnt) {
    const int tid = threadIdx.x;
    const int lane = tid & 63;
    const int w = tid >> 6;
    for (int i = tid; i < 4096; i += 256) perm[i] = -1;
    __syncthreads();
    int base = 0;
    for (int c = 0; c < 16; ++c) {
        const int t = c * 64 + lane;
        const float* xr = x + (long long)t * DMODEL;
        float best = xr[0]; int bi = 0;
        #pragma unroll
        for (int j = 1; j < 16; ++j) { float v = xr[j]; if (v > best) { best = v; bi = j; } }
        const bool match = ((bi & 3) == w);
        unsigned long long mb = __ballot(match);
        int pos = __popcll(mb & ((1ull << lane) - 1ull));
        if (match) perm[w * 1024 + base + pos] = t;
        base += __popcll(mb);
    }
    if (lane == 0) pcnt[w] = (base + 127) & ~127;
}

// ---------------- tconv tile 32k x 64n: full 256B coalesced row reads ----------
__device__ __forceinline__ void tconv_tile64(const float* __restrict__ src,
    unsigned short* __restrict__ dst, int K, int N, int Kp, int kt, int nt,
    float (*t)[65])
{
    const int k0 = kt * 32, n0 = nt * 64;
    const int lane = threadIdx.x & 63, wv = threadIdx.x >> 6;
    #pragma unroll
    for (int i = 0; i < 8; ++i) {
        const int k = k0 + wv * 8 + i;
        const int n = n0 + lane;
        t[wv * 8 + i][lane] = (k < K && n < N) ? src[(long long)k * N + n] : 0.f;
    }
    __syncthreads();
    #pragma unroll
    for (int p = 0; p < 4; ++p) {
        const int nr = p * 16 + (threadIdx.x >> 4);   // 0..63
        const int kp = (threadIdx.x & 15) * 2;        // 0..30
        const int n = n0 + nr;
        if (n < N) {
            us2 wv2; wv2.x = f2bf(t[kp][nr]); wv2.y = f2bf(t[kp + 1][nr]);
            *(us2*)&dst[(long long)n * Kp + k0 + kp] = wv2;
        }
    }
}

__device__ __forceinline__ void ln_row(const float* __restrict__ h,
    const float* __restrict__ g, const float* __restrict__ b,
    unsigned short* __restrict__ out, int row, float* sA, float* sB)
{
    const float* hr = h + (long long)row * DMODEL;
    float s = 0.f, s2 = 0.f;
    for (int j = threadIdx.x; j < DMODEL; j += 256) { float v = hr[j]; s += v; s2 += v * v; }
    #pragma unroll
    for (int o = 32; o; o >>= 1) { s += __shfl_xor(s, o, 64); s2 += __shfl_xor(s2, o, 64); }
    const int lane = threadIdx.x & 63, wid = threadIdx.x >> 6;
    if (lane == 0) { sA[wid] = s; sB[wid] = s2; }
    __syncthreads();
    s = sA[0] + sA[1] + sA[2] + sA[3];
    s2 = sB[0] + sB[1] + sB[2] + sB[3];
    const float mu = s / DMODEL;
    const float rstd = rsqrtf(fmaxf(s2 / DMODEL - mu * mu, 0.f) + 1e-5f);
    unsigned short* orow = out + (long long)row * LDAP;
    for (int j = threadIdx.x; j < LDAP; j += 256) {
        float v = (j < DMODEL) ? (hr[j] - mu) * rstd * g[j] + b[j] : 0.f;
        orow[j] = f2bf(v);
    }
}

#define NB1_QKV (44 * 64)
#define NB1_WO  (44 * 22)
#define NB2_W1  (44 * 43 * 4)
#define NB2_W2  (86 * 22 * 4)

// ---------------- prep1: tconv(wqkv) || tconv(wo) || LN1 ----------------
__global__ __launch_bounds__(256) void prep1_k(
    const float* __restrict__ wqkv_l, const float* __restrict__ wo_l,
    unsigned short* __restrict__ wqkvT, unsigned short* __restrict__ woT,
    const float* __restrict__ h, const float* __restrict__ g,
    const float* __restrict__ bb, unsigned short* __restrict__ lnA)
{
    __shared__ __align__(16) float t[32][65];
    __shared__ float sA[4], sB[4];
    int b = blockIdx.x;
    if (b < NB1_QKV) {
        tconv_tile64(wqkv_l, wqkvT, DMODEL, TD, LDAP, b % 44, b / 44, t);
        return;
    }
    b -= NB1_QKV;
    if (b < NB1_WO) {
        tconv_tile64(wo_l, woT, DMODEL, DMODEL, LDAP, b % 44, b / 44, t);
        return;
    }
    b -= NB1_WO;
    ln_row(h, g, bb, lnA, b, sA, sB);
}

// ---------------- prep2: tconv(w1) || tconv(w2) || LN2 ------------------
__global__ __launch_bounds__(256) void prep2_k(
    const float* __restrict__ w1_l, const float* __restrict__ w2_l,
    unsigned short* __restrict__ w1T, unsigned short* __restrict__ w2T,
    const float* __restrict__ h, const float* __restrict__ g,
    const float* __restrict__ bb, unsigned short* __restrict__ lnA)
{
    __shared__ __align__(16) float t[32][65];
    __shared__ float sA[4], sB[4];
    int b = blockIdx.x;
    if (b < NB2_W1) {
        const int kt = b % 44, rem = b / 44;
        const int nt = rem % 43, z = rem / 43;
        tconv_tile64(w1_l + (long long)z * DMODEL * DFFN,
                     w1T + (long long)z * 2816 * LDAP,
                     DMODEL, DFFN, LDAP, kt, nt, t);
        return;
    }
    b -= NB2_W1;
    if (b < NB2_W2) {
        const int kt = b % 86, rem = b / 86;
        const int nt = rem % 22, z = rem / 22;
        tconv_tile64(w2_l + (long long)z * DFFN * DMODEL,
                     w2T + (long long)z * 1408 * KP2,
                     DFFN, DMODEL, KP2, kt, nt, t);
        return;
    }
    b -= NB2_W2;
    ln_row(h, g, bb, lnA, b, sA, sB);
}

// ---------------- causal row softmax: bf16 in, single global read ----------------
// Each thread owns exactly one us4 (4 elems); row (<=1024) held in registers
// across max/sum/write. Writes zeros beyond n -> P fully defined for PV.
__global__ __launch_bounds__(256) void softmax_k(const unsigned short* __restrict__ scores,
                                                 unsigned short* __restrict__ P,
                                                 float scale) {
    const int i = blockIdx.x;
    const long long rb = ((long long)blockIdx.y * 1024 + i) * 1024;
    const unsigned short* srow = scores + rb;
    unsigned short* prow = P + rb;
    const int n = i + 1;
    const int j0 = threadIdx.x * 4;

    us4 raw = *(const us4*)&srow[j0];
    float v[4];
    #pragma unroll
    for (int e = 0; e < 4; ++e)
        v[e] = (j0 + e < n) ? bf2f(raw[e]) * scale : -1e30f;

    float mx = fmaxf(fmaxf(v[0], v[1]), fmaxf(v[2], v[3]));
    __shared__ float sA[4], sB[4];
    #pragma unroll
    for (int o = 32; o; o >>= 1) mx = fmaxf(mx, __shfl_xor(mx, o, 64));
    const int lane = threadIdx.x & 63, wid = threadIdx.x >> 6;
    if (lane == 0) sA[wid] = mx;
    __syncthreads();
    mx = fmaxf(fmaxf(sA[0], sA[1]), fmaxf(sA[2], sA[3]));

    float p[4]; float sum = 0.f;
    #pragma unroll
    for (int e = 0; e < 4; ++e) {
        p[e] = (j0 + e < n) ? __expf(v[e] - mx) : 0.f;
        sum += p[e];
    }
    #pragma unroll
    for (int o = 32; o; o >>= 1) sum += __shfl_xor(sum, o, 64);
    if (lane == 0) sB[wid] = sum;
    __syncthreads();
    const float inv = 1.f / (sB[0] + sB[1] + sB[2] + sB[3]);

    us4 out;
    #pragma unroll
    for (int e = 0; e < 4; ++e) out[e] = f2bf(p[e] * inv);
    *(us4*)&prow[j0] = out;
}

// ---------------- pipelined bf16 MFMA GEMM, 64x128x64, 8 waves (r17) ----------
// EPI: 0 f32, 1 relu->bf16 zero-kill, 2 f32 accum, 3 scatter-add, 5 qkv-split,
//      6 bf16 compact col z*169, 7 plain bf16 (z-strided).
template<int EPI, bool GATHER, int CAUSAL>
__global__ __launch_bounds__(512) void gemm2_k(
    const unsigned short* __restrict__ A_, int lda, long long zsA,
    const unsigned short* __restrict__ B_, int ldb, long long zsB,
    void* __restrict__ C_, int ldc, long long zsC,
    const float* __restrict__ bias_, long long zsBias,
    const int* __restrict__ perm_, const int* __restrict__ pcnt,
    int N, int Kp,
    unsigned short* __restrict__ q_, unsigned short* __restrict__ k_,
    unsigned short* __restrict__ vt_) {
    const int z = blockIdx.z;
    const int gm0 = blockIdx.y * 64;
    const int n0 = blockIdx.x * 128;
    if (pcnt && gm0 >= pcnt[z]) return;
    if (CAUSAL == 1 && n0 >= gm0 + 64) return;

    const unsigned short* A = A_ + (long long)z * zsA;
    const unsigned short* B = B_ + (long long)z * zsB;
    const float* bias = bias_ ? bias_ + (long long)z * zsBias : nullptr;
    const int* perm = perm_ ? perm_ + (long long)z * 1024 : nullptr;

    __shared__ unsigned short Al[2][64 * 64];    // 16 KB
    __shared__ unsigned short Bl[2][128 * 64];   // 32 KB

    const int tid = threadIdx.x, lane = tid & 63, wid = tid >> 6;   // wid 0..7
    const int wr = wid >> 2, wc = wid & 3;                          // 2M x 4N waves
    const int l15 = lane & 15, lg = lane >> 4;

    const int sr = lane >> 3;             // 0..7
    const int scs = (lane & 7) ^ sr;      // pre-swizzled global 16B-slot

    const unsigned short* gA;
    {
        const int row = wid * 8 + sr;
        int ar = gm0 + row;
        if (GATHER) { const int p = perm[ar]; ar = (p < 0) ? 0 : p; }
        gA = A + (long long)ar * lda + scs * 8;
    }
    const unsigned short* gB[2];
    #pragma unroll
    for (int j = 0; j < 2; ++j)
        gB[j] = B + (long long)(n0 + wid * 16 + j * 8 + sr) * ldb + scs * 8;

    const int ldsA = wid * 512;
    const int ldsB = wid * 1024;

    int nt = Kp >> 6;
    if (CAUSAL == 2) { int ke = gm0 + 64; if (ke > Kp) ke = Kp; nt = ke >> 6; }

    f32x4 acc[2][2] = {};

    #pragma unroll
    for (int tt = 0; tt < 2; ++tt) {
        const int ts = (tt < nt) ? tt : nt - 1;
        const int ko = ts * 64;
        g2l16(gA + ko, &Al[tt & 1][ldsA]);
        g2l16(gB[0] + ko, &Bl[tt & 1][ldsB]);
        g2l16(gB[1] + ko, &Bl[tt & 1][ldsB + 512]);
    }

    for (int t = 0; t < nt; ++t) {
        asm volatile("s_waitcnt vmcnt(3)" ::: "memory");
        __builtin_amdgcn_s_barrier();
        __builtin_amdgcn_sched_barrier(0);
        const int cur = t & 1;
        short8 af[2][2], bfv[2][2];
        #pragma unroll
        for (int m = 0; m < 2; ++m)
            #pragma unroll
            for (int s = 0; s < 2; ++s)
                af[m][s] = *(const short8*)&Al[cur][(wr * 32 + m * 16 + l15) * 64 +
                                                    (((s * 4 + lg) ^ (l15 & 7)) * 8)];
        #pragma unroll
        for (int n = 0; n < 2; ++n)
            #pragma unroll
            for (int s = 0; s < 2; ++s)
                bfv[n][s] = *(const short8*)&Bl[cur][(wc * 32 + n * 16 + l15) * 64 +
                                                     (((s * 4 + lg) ^ (l15 & 7)) * 8)];
        #pragma unroll
        for (int s = 0; s < 2; ++s)
            #pragma unroll
            for (int m = 0; m < 2; ++m)
                #pragma unroll
                for (int n = 0; n < 2; ++n)
                    acc[m][n] = __builtin_amdgcn_mfma_f32_16x16x32_bf16(af[m][s], bfv[n][s], acc[m][n], 0, 0, 0);
        __builtin_amdgcn_sched_barrier(0);
        __builtin_amdgcn_s_barrier();
        __builtin_amdgcn_sched_barrier(0);
        {
            const int ts = (t + 2 < nt) ? t + 2 : nt - 1;
            const int ko = ts * 64;
            g2l16(gA + ko, &Al[cur][ldsA]);
            g2l16(gB[0] + ko, &Bl[cur][ldsB]);
            g2l16(gB[1] + ko, &Bl[cur][ldsB + 512]);
        }
    }

    // DRAIN: no LDS-DMA may be in flight at s_endpgm (round-3 race)
    asm volatile("s_waitcnt vmcnt(0) lgkmcnt(0)" ::: "memory");

    const int lq = lg * 4;
    #pragma unroll
    for (int m = 0; m < 2; ++m) {
        const int trow = wr * 32 + m * 16 + lq;
        #pragma unroll
        for (int n = 0; n < 2; ++n) {
            const int col = n0 + wc * 32 + n * 16 + l15;
            if (col >= N) continue;
            const float bv = bias ? bias[col] : 0.f;
            if (EPI == 5) {
                const int role = col / 1352;
                const int within = col - role * 1352;
                const int hh = within / 169;
                const int dd = within - hh * 169;
                if (role == 2) {
                    us4 pk;
                    #pragma unroll
                    for (int r = 0; r < 4; ++r) pk[r] = f2bf(acc[m][n][r] + bv);
                    *(us4*)&vt_[(long long)(hh * 256 + dd) * 1024 + gm0 + trow] = pk;
                } else {
                    unsigned short* dstb = role ? k_ : q_;
                    #pragma unroll
                    for (int r = 0; r < 4; ++r)
                        dstb[(long long)(gm0 + trow + r) * QS + hh * HP + dd] =
                            f2bf(acc[m][n][r] + bv);
                }
            } else {
                #pragma unroll
                for (int r = 0; r < 4; ++r) {
                    const int grow = gm0 + trow + r;
                    const float v = acc[m][n][r] + bv;
                    if (EPI == 0) {
                        ((float*)C_)[(long long)z * zsC + (long long)grow * ldc + col] = v;
                    } else if (EPI == 1) {
                        const int tok = perm[grow];
                        ((unsigned short*)C_)[(long long)z * zsC + (long long)grow * ldc + col] =
                            (tok >= 0) ? f2bf(fmaxf(v, 0.f)) : (unsigned short)0;
                    } else if (EPI == 2) {
                        ((float*)C_)[(long long)grow * ldc + col] += v;
                    } else if (EPI == 3) {
                        const int tok = perm[grow];
                        if (tok >= 0) ((float*)C_)[(long long)tok * ldc + col] += v;
                    } else if (EPI == 6) {
                        ((unsigned short*)C_)[(long long)grow * ldc + z * 169 + col] = f2bf(v);
                    } else if (EPI == 7) {
                        ((unsigned short*)C_)[(long long)z * zsC + (long long)grow * ldc + col] = f2bf(v);
                    }
                }
            }
        }
    }
}

extern "C" void kernel_launch(void* const* d_in, const int* in_sizes, int n_in,
                              void* d_out, int out_size, void* d_ws, size_t ws_size,
                              hipStream_t stream) {
    const float* x     = (const float*)d_in[0];
    const float* ln1_g = (const float*)d_in[1];
    const float* ln1_b = (const float*)d_in[2];
    const float* wqkv  = (const float*)d_in[3];
    const float* bqkv  = (const float*)d_in[4];
    const float* wo    = (const float*)d_in[5];
    const float* bo    = (const float*)d_in[6];
    const float* ln2_g = (const float*)d_in[7];
    const float* ln2_b = (const float*)d_in[8];
    const float* w1    = (const float*)d_in[9];
    const float* b1    = (const float*)d_in[10];
    const float* w2    = (const float*)d_in[11];
    const float* b2    = (const float*)d_in[12];

    float* h = (float*)d_out;

    char* w = (char*)d_ws;
    auto alloc = [&](size_t bytes) { void* p = w; w += (bytes + 255) & ~255ull; return p; };
    unsigned short* lnA   = (unsigned short*)alloc((size_t)S_LEN * LDAP * 2);
    unsigned short* qb    = (unsigned short*)alloc((size_t)S_LEN * QS * 2);
    unsigned short* kb    = (unsigned short*)alloc((size_t)S_LEN * QS * 2);
    unsigned short* VT    = (unsigned short*)alloc((size_t)NHEAD * 256 * 1024 * 2);
    unsigned short* obufb = (unsigned short*)alloc((size_t)S_LEN * LDAP * 2);
    unsigned short* hid   = (unsigned short*)alloc((size_t)4096 * KP2 * 2);
    unsigned short* wqkvT = (unsigned short*)alloc((size_t)4096 * LDAP * 2);
    unsigned short* woT   = (unsigned short*)alloc((size_t)1408 * LDAP * 2);
    char*           U     = (char*)alloc((size_t)64000000);   // union (time-aliased, L3-hot)
    int* perm = (int*)alloc(4096 * 4);
    int* pcnt = (int*)alloc(64);

    unsigned short* scoresb = (unsigned short*)U;                                    // 16.8 MB
    unsigned short* Pbuf    = (unsigned short*)(U + (size_t)NHEAD * 1024 * 1024 * 2); // 16.8 MB
    unsigned short* w1T     = (unsigned short*)U;                                    // 31.7 MB
    unsigned short* w2T     = (unsigned short*)(U + (size_t)4 * 2816 * LDAP * 2);    // 31.0 MB

    hipMemcpyAsync(h, x, (size_t)S_LEN * DMODEL * 4, hipMemcpyDeviceToDevice, stream);
    // q/k head-pad slots enter the scores MFMA -> must be zero
    hipMemsetAsync(qb, 0, (size_t)S_LEN * QS * 2, stream);
    hipMemsetAsync(kb, 0, (size_t)S_LEN * QS * 2, stream);
    route_k<<<1, 256, 0, stream>>>(x, perm, pcnt);

    const float scale = 1.0f / 13.0f;

    for (int l = 0; l < NLAYER; ++l) {
        const float* wqkv_l = wqkv + (long long)l * DMODEL * TD;
        const float* wo_l   = wo   + (long long)l * DMODEL * DMODEL;
        const float* w1_l   = w1   + (long long)l * 4 * DMODEL * DFFN;
        const float* w2_l   = w2   + (long long)l * 4 * DFFN * DMODEL;

        // fused: tconv(wqkv) || tconv(wo) || LN1
        prep1_k<<<NB1_QKV + NB1_WO + 1024, 256, 0, stream>>>(
            wqkv_l, wo_l, wqkvT, woT, h, ln1_g + l * DMODEL, ln1_b + l * DMODEL, lnA);
        // QKV -> split bf16 q/k (head-padded) + V transposed
        gemm2_k<5, false, 0><<<dim3(32, 16, 1), 512, 0, stream>>>(
            lnA, LDAP, 0, wqkvT, LDAP, 0, nullptr, 0, 0,
            bqkv + l * TD, 0, nullptr, nullptr, TD, LDAP, qb, kb, VT);
        // scores = q @ k^T per head (causal tiles only), bf16
        gemm2_k<7, false, 1><<<dim3(8, 16, 8), 512, 0, stream>>>(
            qb, QS, HP, kb, QS, HP, scoresb, 1024, 1024 * 1024,
            nullptr, 0, nullptr, nullptr, 1024, HP, nullptr, nullptr, nullptr);
        softmax_k<<<dim3(1024, NHEAD), 256, 0, stream>>>(scoresb, Pbuf, scale);
        // o = P @ v per head -> compact bf16 [1024][1408]
        gemm2_k<6, false, 2><<<dim3(2, 16, 8), 512, 0, stream>>>(
            Pbuf, 1024, 1024 * 1024, VT, 1024, 256 * 1024, obufb, LDAP, 0,
            nullptr, 0, nullptr, nullptr, HDIM, 1024, nullptr, nullptr, nullptr);
        // h += o @ wo + bo
        gemm2_k<2, false, 0><<<dim3(11, 16, 1), 512, 0, stream>>>(
            obufb, LDAP, 0, woT, LDAP, 0, h, DMODEL, 0,
            bo + l * DMODEL, 0, nullptr, nullptr, DMODEL, LDAP, nullptr, nullptr, nullptr);

        // fused: tconv(w1) || tconv(w2) || LN2  (overwrites scoresb/Pbuf union; both dead)
        prep2_k<<<NB2_W1 + NB2_W2 + 1024, 256, 0, stream>>>(
            w1_l, w2_l, w1T, w2T, h, ln2_g + l * DMODEL, ln2_b + l * DMODEL, lnA);
        // hid = relu(gather(lnA) @ w1[e] + b1[e]) -> bf16
        gemm2_k<1, true, 0><<<dim3(22, 16, 4), 512, 0, stream>>>(
            lnA, LDAP, 0, w1T, LDAP, (long long)2816 * LDAP,
            hid, KP2, (long long)1024 * KP2,
            b1 + (long long)l * 4 * DFFN, DFFN, perm, pcnt, DFFN, LDAP,
            nullptr, nullptr, nullptr);
        // h[tok] += hid @ w2[e] + b2[e]
        gemm2_k<3, false, 0><<<dim3(11, 16, 4), 512, 0, stream>>>(
            hid, KP2, (long long)1024 * KP2, w2T, KP2, (long long)1408 * KP2,
            h, DMODEL, 0,
            b2 + (long long)l * 4 * DMODEL, DMODEL, perm, pcnt, DMODEL, KP2,
            nullptr, nullptr, nullptr);
    }
}